// Round 6
// baseline (450.048 us; speedup 1.0000x reference)
//
#include <hip/hip_runtime.h>

constexpr int T_ = 4, B_ = 32, N_ = 1024, D_ = 512, O_ = 512, OP_ = 256;
constexpr int M_ = T_ * B_ * N_;
constexpr unsigned CAP = 1u * 1024 * 1024;

// ---- ws layout (bytes) ----
constexpr size_t WS_CNT  = 0;
constexpr size_t WS_WP   = 1u << 20;                  // 1 MiB fragment-ordered W (hi+lo)
constexpr size_t WS_LIST = WS_WP + (1u << 20);
constexpr size_t WS_NEED = WS_LIST + (size_t)CAP * 4;

typedef __attribute__((ext_vector_type(8))) short bf8;
typedef __attribute__((ext_vector_type(4))) float f4;

union BF8U { unsigned u[4]; bf8 v; };

__device__ __forceinline__ unsigned cvtpk(float x0, float x1) {
    unsigned r;
    asm("v_cvt_pk_bf16_f32 %0, %1, %2" : "=v"(r) : "v"(x0), "v"(x1));
    return r;
}
__device__ __forceinline__ float hi_lo_f(unsigned u) { return __uint_as_float(u << 16); }
__device__ __forceinline__ float hi_hi_f(unsigned u) { return __uint_as_float(u & 0xffff0000u); }

// ---------------- W prep: fragment-ordered hi/lo split + cnt reset ----------------
// wp chunk id c = [panel:8][j:16][q:8][lane:64], 16B each; q = term*4 + cf*2 + eo.
__global__ __launch_bounds__(256) void k_wprep(const float* __restrict__ W,
                                               unsigned short* __restrict__ wp,
                                               unsigned* __restrict__ cnt)
{
    if (blockIdx.x == 0 && threadIdx.x == 0) *cnt = 0u;
    const int c = blockIdx.x * 256 + threadIdx.x;      // 0..65535
    const int lane = c & 63, q = (c >> 6) & 7, j = (c >> 9) & 15, panel = c >> 13;
    const int colblk = panel >> 1, half = panel & 1;
    const int term = q >> 2, cf = (q >> 1) & 1, eo = q & 1;
    const int col = colblk * 128 + half * 64 + cf * 32 + 2 * (lane & 15) + eo;
    const int k0 = j * 32 + (lane >> 4) * 8;
    const float* src = W + (size_t)col * 512 + k0;
    const float4 v0 = *(const float4*)(src);
    const float4 v1 = *(const float4*)(src + 4);
    const float xs[8] = {v0.x, v0.y, v0.z, v0.w, v1.x, v1.y, v1.z, v1.w};
    unsigned o[4];
    #pragma unroll
    for (int p = 0; p < 4; ++p) {
        const unsigned hi = cvtpk(xs[2 * p], xs[2 * p + 1]);
        if (term == 0) {
            o[p] = hi;
        } else {
            const float l0 = xs[2 * p] - hi_lo_f(hi);
            const float l1 = xs[2 * p + 1] - hi_hi_f(hi);
            o[p] = cvtpk(l0, l1);
        }
    }
    *(uint4*)(wp + (size_t)c * 8) = make_uint4(o[0], o[1], o[2], o[3]);
}

// ---------------- LDS-free, barrier-free wave-private GEMM + BN/pool/LIF + flag ------
__global__ __launch_bounds__(256, 2) void k_gemm(
    const float* __restrict__ x, const unsigned short* __restrict__ wp,
    const float* __restrict__ gamma, const float* __restrict__ beta,
    const float* __restrict__ rmean, const float* __restrict__ rvar,
    float* __restrict__ out, unsigned* __restrict__ cnt, unsigned* __restrict__ list)
{
    const int tid  = threadIdx.x;
    const int lane = tid & 63;
    const int wid  = tid >> 6;

    const int dd = blockIdx.x;                  // XCD-aware swizzle
    const int w  = (dd & 7) * 512 + (dd >> 3);
    const int colblk = w & 3, rowblk = w >> 2;
    const int c0  = colblk * 128;
    const int wr0 = (wid >> 1) * 64, wc0 = (wid & 1) * 64;

    // ---- BN constants (drained before the vmcnt ledger starts) ----
    float invE[2], addE[2], invO[2], addO[2];
    #pragma unroll
    for (int cf = 0; cf < 2; ++cf) {
        int cE = c0 + wc0 + cf * 32 + 2 * (lane & 15);
        int cO = cE + 1;
        float ivE = gamma[cE] / sqrtf(rvar[cE] + 1e-5f);
        float ivO = gamma[cO] / sqrtf(rvar[cO] + 1e-5f);
        invE[cf] = ivE; addE[cf] = beta[cE] - rmean[cE] * ivE;
        invO[cf] = ivO; addO[cf] = beta[cO] - rmean[cO] * ivO;
    }
    asm volatile("s_waitcnt vmcnt(0)" ::: "memory");
    __builtin_amdgcn_sched_barrier(0);

    // ---- A per-lane voffsets (bytes), one per rf; k-imm added per step ----
    unsigned vA0, vA1, vA2, vA3;
    {
        #pragma unroll
        for (int rf = 0; rf < 4; ++rf) {
            const int row = wr0 + rf * 16 + (lane & 15);   // row = site_local*4 + t
            const int t = row & 3, sl = row >> 2;
            const unsigned v = (unsigned)(t * 32768 + rowblk * 32 + sl) * 2048u
                             + ((unsigned)(lane >> 4) << 5);
            if (rf == 0) vA0 = v; else if (rf == 1) vA1 = v;
            else if (rf == 2) vA2 = v; else vA3 = v;
        }
    }
    // ---- B voffset base ----
    const int panel = colblk * 2 + (wid & 1);
    const unsigned vBb = (unsigned)panel * 131072u + (unsigned)lane * 16u;

    f4 accE[4][2], accO[4][2];
    #pragma unroll
    for (int i = 0; i < 4; ++i)
        #pragma unroll
        for (int j = 0; j < 2; ++j) { accE[i][j] = (f4)0.0f; accO[i][j] = (f4)0.0f; }

    float4 A0a, A0b, A1a, A1b, A2a, A2b, A3a, A3b;
    bf8 Bf[8];
    bf8 ah[4], am[4];

#define SCHED __builtin_amdgcn_sched_barrier(0)

#define ALOAD(J)                                                                      \
    do {                                                                              \
        asm volatile("global_load_dwordx4 %0, %1, %2 offset:%3"                       \
                     : "=v"(A0a) : "v"(vA0), "s"(x), "n"((J) * 128) : "memory");      \
        asm volatile("global_load_dwordx4 %0, %1, %2 offset:%3"                       \
                     : "=v"(A0b) : "v"(vA0), "s"(x), "n"((J) * 128 + 16) : "memory"); \
        asm volatile("global_load_dwordx4 %0, %1, %2 offset:%3"                       \
                     : "=v"(A1a) : "v"(vA1), "s"(x), "n"((J) * 128) : "memory");      \
        asm volatile("global_load_dwordx4 %0, %1, %2 offset:%3"                       \
                     : "=v"(A1b) : "v"(vA1), "s"(x), "n"((J) * 128 + 16) : "memory"); \
        asm volatile("global_load_dwordx4 %0, %1, %2 offset:%3"                       \
                     : "=v"(A2a) : "v"(vA2), "s"(x), "n"((J) * 128) : "memory");      \
        asm volatile("global_load_dwordx4 %0, %1, %2 offset:%3"                       \
                     : "=v"(A2b) : "v"(vA2), "s"(x), "n"((J) * 128 + 16) : "memory"); \
        asm volatile("global_load_dwordx4 %0, %1, %2 offset:%3"                       \
                     : "=v"(A3a) : "v"(vA3), "s"(x), "n"((J) * 128) : "memory");      \
        asm volatile("global_load_dwordx4 %0, %1, %2 offset:%3"                       \
                     : "=v"(A3b) : "v"(vA3), "s"(x), "n"((J) * 128 + 16) : "memory"); \
    } while (0)

#define BLOADH(CF, J)                                                                 \
    do {                                                                              \
        const unsigned vb  = vBb + (unsigned)(J) * 8192u;                             \
        const unsigned vb2 = vb + 4096u;                                              \
        asm volatile("global_load_dwordx4 %0, %1, %2 offset:%3"                       \
                     : "=v"(Bf[(CF) * 2]) : "v"(vb), "s"(wp),                         \
                       "n"((CF) * 2048) : "memory");                                  \
        asm volatile("global_load_dwordx4 %0, %1, %2 offset:%3"                       \
                     : "=v"(Bf[(CF) * 2 + 1]) : "v"(vb), "s"(wp),                     \
                       "n"((CF) * 2048 + 1024) : "memory");                           \
        asm volatile("global_load_dwordx4 %0, %1, %2 offset:%3"                       \
                     : "=v"(Bf[4 + (CF) * 2]) : "v"(vb2), "s"(wp),                    \
                       "n"((CF) * 2048) : "memory");                                  \
        asm volatile("global_load_dwordx4 %0, %1, %2 offset:%3"                       \
                     : "=v"(Bf[5 + (CF) * 2]) : "v"(vb2), "s"(wp),                    \
                       "n"((CF) * 2048 + 1024) : "memory");                           \
    } while (0)

#define CONV1(RF, VA, VB)                                                             \
    do {                                                                              \
        const unsigned h0 = cvtpk(VA.x, VA.y), h1 = cvtpk(VA.z, VA.w);                \
        const unsigned h2 = cvtpk(VB.x, VB.y), h3 = cvtpk(VB.z, VB.w);                \
        const unsigned l0 = cvtpk(VA.x - hi_lo_f(h0), VA.y - hi_hi_f(h0));            \
        const unsigned l1 = cvtpk(VA.z - hi_lo_f(h1), VA.w - hi_hi_f(h1));            \
        const unsigned l2 = cvtpk(VB.x - hi_lo_f(h2), VB.y - hi_hi_f(h2));            \
        const unsigned l3 = cvtpk(VB.z - hi_lo_f(h3), VB.w - hi_hi_f(h3));            \
        BF8U uh; uh.u[0] = h0; uh.u[1] = h1; uh.u[2] = h2; uh.u[3] = h3;              \
        ah[RF] = uh.v;                                                                \
        BF8U um; um.u[0] = l0; um.u[1] = l1; um.u[2] = l2; um.u[3] = l3;              \
        am[RF] = um.v;                                                                \
    } while (0)

#define CONVERT                                                                       \
    do {                                                                              \
        CONV1(0, A0a, A0b);                                                           \
        CONV1(1, A1a, A1b);                                                           \
        CONV1(2, A2a, A2b);                                                           \
        CONV1(3, A3a, A3b);                                                           \
    } while (0)

#define MFMACF(CF)                                                                    \
    do {                                                                              \
        _Pragma("unroll") for (int rf = 0; rf < 4; ++rf) {                            \
            accE[rf][CF] = __builtin_amdgcn_mfma_f32_16x16x32_bf16(                   \
                ah[rf], Bf[(CF) * 2], accE[rf][CF], 0, 0, 0);                         \
            accE[rf][CF] = __builtin_amdgcn_mfma_f32_16x16x32_bf16(                   \
                ah[rf], Bf[4 + (CF) * 2], accE[rf][CF], 0, 0, 0);                     \
            accE[rf][CF] = __builtin_amdgcn_mfma_f32_16x16x32_bf16(                   \
                am[rf], Bf[(CF) * 2], accE[rf][CF], 0, 0, 0);                         \
            accO[rf][CF] = __builtin_amdgcn_mfma_f32_16x16x32_bf16(                   \
                ah[rf], Bf[(CF) * 2 + 1], accO[rf][CF], 0, 0, 0);                     \
            accO[rf][CF] = __builtin_amdgcn_mfma_f32_16x16x32_bf16(                   \
                ah[rf], Bf[5 + (CF) * 2], accO[rf][CF], 0, 0, 0);                     \
            accO[rf][CF] = __builtin_amdgcn_mfma_f32_16x16x32_bf16(                   \
                am[rf], Bf[(CF) * 2 + 1], accO[rf][CF], 0, 0, 0);                     \
        }                                                                             \
    } while (0)

// Ledger per step J (wave-private): start outstanding = {A(J):8 oldest, B(J):8}.
// vmcnt(8) -> A(J) ready; convert; issue A(J+1); vmcnt(8) -> B(J) ready;
// MFMA cf0; issue B(J+1).cf0; MFMA cf1; issue B(J+1).cf1.
#define ITER(J, JN)                                                                   \
    do {                                                                              \
        asm volatile("s_waitcnt vmcnt(8)" ::: "memory");                              \
        SCHED;                                                                        \
        CONVERT;                                                                      \
        SCHED;                                                                        \
        ALOAD(JN);                                                                    \
        SCHED;                                                                        \
        asm volatile("s_waitcnt vmcnt(8)" ::: "memory");                              \
        SCHED;                                                                        \
        __builtin_amdgcn_s_setprio(1);                                                \
        MFMACF(0);                                                                    \
        __builtin_amdgcn_s_setprio(0);                                                \
        SCHED;                                                                        \
        BLOADH(0, JN);                                                                \
        SCHED;                                                                        \
        __builtin_amdgcn_s_setprio(1);                                                \
        MFMACF(1);                                                                    \
        __builtin_amdgcn_s_setprio(0);                                                \
        SCHED;                                                                        \
        BLOADH(1, JN);                                                                \
        SCHED;                                                                        \
    } while (0)

    // ---- prologue: A(0) then B(0) ----
    SCHED;
    ALOAD(0);
    SCHED;
    BLOADH(0, 0);
    BLOADH(1, 0);
    SCHED;

    ITER(0, 1);   ITER(1, 2);   ITER(2, 3);   ITER(3, 4);
    ITER(4, 5);   ITER(5, 6);   ITER(6, 7);   ITER(7, 8);
    ITER(8, 9);   ITER(9, 10);  ITER(10, 11); ITER(11, 12);
    ITER(12, 13); ITER(13, 14); ITER(14, 15);

    // ---- final step J=15: no new issues ----
    asm volatile("s_waitcnt vmcnt(8)" ::: "memory");
    SCHED;
    CONVERT;
    SCHED;
    asm volatile("s_waitcnt vmcnt(0)" ::: "memory");
    SCHED;
    __builtin_amdgcn_s_setprio(1);
    MFMACF(0);
    MFMACF(1);
    __builtin_amdgcn_s_setprio(0);
    SCHED;

#undef ITER
#undef MFMACF
#undef CONVERT
#undef CONV1
#undef BLOADH
#undef ALOAD
#undef SCHED

    // ---- epilogue: BN -> pool -> LIF, flag near-threshold pipelines ----
    #pragma unroll
    for (int rf = 0; rf < 4; ++rf) {
        const int site = rowblk * 32 + (wid >> 1) * 16 + rf * 4 + (lane >> 4);
        const int bI = site >> 10, nI = site & 1023;
        #pragma unroll
        for (int cf = 0; cf < 2; ++cf) {
            const int op = ((c0 + wc0 + cf * 32) >> 1) + (lane & 15);
            float v = 0.0f;
            bool flg = false;
            #pragma unroll
            for (int t = 0; t < 4; ++t) {
                float hE = accE[rf][cf][t] * invE[cf] + addE[cf];
                float hO = accO[rf][cf][t] * invO[cf] + addO[cf];
                float m = fmaxf(hE, hO);
                v = (v + m) * 0.5f;
                float dv = v - 1.0f;
                bool sp = dv >= 0.0f;
                out[(((size_t)t * 32 + bI) * 1024 + nI) * 256 + op] = sp ? 1.0f : 0.0f;
                flg |= (fabsf(dv) < 2e-4f);
                if (sp) v = 0.0f;
            }
            if (flg) {
                unsigned idx = atomicAdd(cnt, 1u);
                if (idx < CAP) list[idx] = ((unsigned)site << 8) | (unsigned)op;
            }
        }
    }
}

// ---------------- exact f64 repair of flagged pipelines ----------------
__global__ __launch_bounds__(256) void k_repair(
    const float* __restrict__ x, const float* __restrict__ W,
    const float* __restrict__ gamma, const float* __restrict__ beta,
    const float* __restrict__ rmean, const float* __restrict__ rvar,
    float* __restrict__ out, const unsigned* __restrict__ cnt,
    const unsigned* __restrict__ list)
{
    unsigned count = *cnt;
    if (count > CAP) count = CAP;
    for (unsigned j = blockIdx.x * 256 + threadIdx.x; j < count; j += 256u * 256u) {
        const unsigned e = list[j];
        const int op = e & 255;
        const int site = e >> 8;
        const int bI = site >> 10, nI = site & 1023;

        double h[4][2];
        #pragma unroll
        for (int p = 0; p < 2; ++p) {
            const int c = 2 * op + p;
            const float* Wr = W + (size_t)c * D_;
            #pragma unroll
            for (int t = 0; t < 4; ++t) {
                const float* xr = x + (((size_t)t * 32 + bI) * 1024 + nI) * D_;
                double s0 = 0, s1 = 0, s2 = 0, s3 = 0;
                for (int d = 0; d < D_; d += 4) {
                    float4 xv = *(const float4*)(xr + d);
                    float4 wv = *(const float4*)(Wr + d);
                    s0 = fma((double)xv.x, (double)wv.x, s0);
                    s1 = fma((double)xv.y, (double)wv.y, s1);
                    s2 = fma((double)xv.z, (double)wv.z, s2);
                    s3 = fma((double)xv.w, (double)wv.w, s3);
                }
                h[t][p] = (s0 + s1) + (s2 + s3);
            }
        }
        double iv[2], ad[2];
        #pragma unroll
        for (int p = 0; p < 2; ++p) {
            const int c = 2 * op + p;
            iv[p] = (double)gamma[c] / sqrt((double)rvar[c] + 1e-5);
            ad[p] = (double)beta[c] - (double)rmean[c] * iv[p];
        }
        double v = 0.0;
        #pragma unroll
        for (int t = 0; t < 4; ++t) {
            double h0 = h[t][0] * iv[0] + ad[0];
            double h1 = h[t][1] * iv[1] + ad[1];
            double m = fmax(h0, h1);
            v = (v + m) * 0.5;
            const bool sp = (v >= 1.0);
            out[(((size_t)t * 32 + bI) * 1024 + nI) * 256 + op] = sp ? 1.0f : 0.0f;
            if (sp) v = 0.0;
        }
    }
}

// ---------------- fallback (round-1 exact f64 kernel) ----------------
constexpr int FB_SITES = 32, FB_ROWS = 128, FB_BN = 64, FB_BK = 16;

__global__ __launch_bounds__(256)
void snn_fused_f64(const float* __restrict__ x, const float* __restrict__ W,
                   const float* __restrict__ gamma, const float* __restrict__ beta,
                   const float* __restrict__ rmean, const float* __restrict__ rvar,
                   float* __restrict__ out)
{
    __shared__ float As[FB_BK][FB_ROWS];
    __shared__ float Bs[FB_BK][FB_BN];
    const int tid = threadIdx.x;
    const int tx = tid & 15, ty = tid >> 4;
    const int c0 = blockIdx.x * FB_BN;
    const int site_base = blockIdx.y * FB_SITES;
    const int b = site_base / N_, n0 = site_base % N_;
    const int lrow = tid >> 1, lk = (tid & 1) * 8;
    const int s_l = lrow >> 2, t_l = lrow & 3;
    const float* xrow = x + (size_t)((t_l * B_ + b) * N_ + (n0 + s_l)) * D_ + lk;
    const int wc = tid & 63, wk = (tid >> 6) * 4;
    const float* wrow = W + (size_t)(c0 + wc) * D_ + wk;
    double acc[8][4];
    #pragma unroll
    for (int i = 0; i < 8; ++i)
        #pragma unroll
        for (int j = 0; j < 4; ++j) acc[i][j] = 0.0;
    for (int k0 = 0; k0 < D_; k0 += FB_BK) {
        const float4 a0 = *(const float4*)(xrow + k0);
        const float4 a1 = *(const float4*)(xrow + k0 + 4);
        const float4 w4 = *(const float4*)(wrow + k0);
        As[lk + 0][lrow] = a0.x; As[lk + 1][lrow] = a0.y; As[lk + 2][lrow] = a0.z; As[lk + 3][lrow] = a0.w;
        As[lk + 4][lrow] = a1.x; As[lk + 5][lrow] = a1.y; As[lk + 6][lrow] = a1.z; As[lk + 7][lrow] = a1.w;
        Bs[wk + 0][wc] = w4.x; Bs[wk + 1][wc] = w4.y; Bs[wk + 2][wc] = w4.z; Bs[wk + 3][wc] = w4.w;
        __syncthreads();
        #pragma unroll
        for (int k = 0; k < FB_BK; ++k) {
            const float4 af0 = *(const float4*)&As[k][ty * 8];
            const float4 af1 = *(const float4*)&As[k][ty * 8 + 4];
            const float4 bf = *(const float4*)&Bs[k][tx * 4];
            const double ad[8] = {(double)af0.x, (double)af0.y, (double)af0.z, (double)af0.w,
                                  (double)af1.x, (double)af1.y, (double)af1.z, (double)af1.w};
            const double bd[4] = {(double)bf.x, (double)bf.y, (double)bf.z, (double)bf.w};
            #pragma unroll
            for (int i = 0; i < 8; ++i)
                #pragma unroll
                for (int j = 0; j < 4; ++j) acc[i][j] = fma(ad[i], bd[j], acc[i][j]);
        }
        __syncthreads();
    }
    double invd[4], addd[4];
    #pragma unroll
    for (int j = 0; j < 4; ++j) {
        const int c = c0 + tx * 4 + j;
        const double ivv = (double)gamma[c] / sqrt((double)rvar[c] + 1e-5);
        invd[j] = ivv; addd[j] = (double)beta[c] - (double)rmean[c] * ivv;
    }
    #pragma unroll
    for (int si = 0; si < 2; ++si) {
        const int n = n0 + ty * 2 + si;
        #pragma unroll
        for (int p = 0; p < 2; ++p) {
            const int op = (c0 >> 1) + tx * 2 + p;
            double v = 0.0;
            #pragma unroll
            for (int t = 0; t < 4; ++t) {
                const int i = si * 4 + t;
                const double h0 = acc[i][2 * p] * invd[2 * p] + addd[2 * p];
                const double h1 = acc[i][2 * p + 1] * invd[2 * p + 1] + addd[2 * p + 1];
                const double m = fmax(h0, h1);
                v = v + (m - v) * 0.5;
                const bool sp = (v >= 1.0);
                out[((size_t)(t * B_ + b) * N_ + n) * OP_ + op] = sp ? 1.0f : 0.0f;
                if (sp) v = 0.0;
            }
        }
    }
}

extern "C" void kernel_launch(void* const* d_in, const int* in_sizes, int n_in,
                              void* d_out, int out_size, void* d_ws, size_t ws_size,
                              hipStream_t stream)
{
    const float* x     = (const float*)d_in[0];
    const float* W     = (const float*)d_in[1];
    const float* gamma = (const float*)d_in[2];
    const float* beta  = (const float*)d_in[3];
    const float* rmean = (const float*)d_in[4];
    const float* rvar  = (const float*)d_in[5];
    float* out = (float*)d_out;

    if (ws_size < WS_NEED) {
        dim3 grid(O_ / FB_BN, (B_ * N_) / FB_SITES);
        snn_fused_f64<<<grid, dim3(256), 0, stream>>>(x, W, gamma, beta, rmean, rvar, out);
        return;
    }

    char* ws = (char*)d_ws;
    unsigned* cnt = (unsigned*)(ws + WS_CNT);
    unsigned short* wp = (unsigned short*)(ws + WS_WP);
    unsigned* list = (unsigned*)(ws + WS_LIST);

    k_wprep<<<256, 256, 0, stream>>>(W, wp, cnt);
    k_gemm<<<4096, 256, 0, stream>>>(x, wp, gamma, beta, rmean, rvar, out, cnt, list);
    k_repair<<<256, 256, 0, stream>>>(x, W, gamma, beta, rmean, rvar, out, cnt, list);
}

// Round 8
// 387.546 us; speedup vs baseline: 1.1613x; 1.1613x over previous
//
#include <hip/hip_runtime.h>

constexpr int T_ = 4, B_ = 32, N_ = 1024, D_ = 512, O_ = 512, OP_ = 256;
constexpr int M_ = T_ * B_ * N_;
constexpr unsigned CAP = 1u * 1024 * 1024;

// ---- ws layout (bytes) ----
constexpr size_t WS_CNT  = 0;
constexpr size_t WS_WP   = 1u << 20;                  // 1 MiB fragment-ordered W (hi+lo)
constexpr size_t WS_LIST = WS_WP + (1u << 20);
constexpr size_t WS_NEED = WS_LIST + (size_t)CAP * 4;

typedef __attribute__((ext_vector_type(8))) short bf8;
typedef __attribute__((ext_vector_type(4))) float f4;

__device__ __forceinline__ unsigned cvtpk(float x0, float x1) {
    unsigned r;
    asm("v_cvt_pk_bf16_f32 %0, %1, %2" : "=v"(r) : "v"(x0), "v"(x1));
    return r;
}
__device__ __forceinline__ float hi_lo_f(unsigned u) { return __uint_as_float(u << 16); }
__device__ __forceinline__ float hi_hi_f(unsigned u) { return __uint_as_float(u & 0xffff0000u); }

// ---------------- W prep: fragment-ordered hi/lo split + cnt reset ----------------
// wp chunk id c = [panel:8][j:16][q:8][lane:64], 16B each; q = term*4 + cfh*2 + eo.
__global__ __launch_bounds__(256) void k_wprep(const float* __restrict__ W,
                                               unsigned short* __restrict__ wp,
                                               unsigned* __restrict__ cnt)
{
    if (blockIdx.x == 0 && threadIdx.x == 0) *cnt = 0u;
    const int c = blockIdx.x * 256 + threadIdx.x;      // 0..65535
    const int lane = c & 63, q = (c >> 6) & 7, j = (c >> 9) & 15, panel = c >> 13;
    const int colblk = panel >> 1, half = panel & 1;
    const int term = q >> 2, cf = (q >> 1) & 1, eo = q & 1;
    const int col = colblk * 128 + half * 64 + cf * 32 + 2 * (lane & 15) + eo;
    const int k0 = j * 32 + (lane >> 4) * 8;
    const float* src = W + (size_t)col * 512 + k0;
    const float4 v0 = *(const float4*)(src);
    const float4 v1 = *(const float4*)(src + 4);
    const float xs[8] = {v0.x, v0.y, v0.z, v0.w, v1.x, v1.y, v1.z, v1.w};
    unsigned o[4];
    #pragma unroll
    for (int p = 0; p < 4; ++p) {
        const unsigned hi = cvtpk(xs[2 * p], xs[2 * p + 1]);
        if (term == 0) {
            o[p] = hi;
        } else {
            const float l0 = xs[2 * p] - hi_lo_f(hi);
            const float l1 = xs[2 * p + 1] - hi_hi_f(hi);
            o[p] = cvtpk(l0, l1);
        }
    }
    *(uint4*)(wp + (size_t)c * 8) = make_uint4(o[0], o[1], o[2], o[3]);
}

// -------- barrier-free wave-private-LDS GEMM + BN/pool/LIF + flag --------
// Block: 4 waves; wave w owns 32 rows (2 rf) x 128 cols (4 cf). LDS 8KB/wave
// (2 bufs x 2 terms x 32 rows x 64B). No s_barrier in the K-loop.
__global__ __launch_bounds__(256, 2) void k_gemm(
    const float* __restrict__ x, const unsigned short* __restrict__ wp,
    const float* __restrict__ gamma, const float* __restrict__ beta,
    const float* __restrict__ rmean, const float* __restrict__ rvar,
    float* __restrict__ out, unsigned* __restrict__ cnt, unsigned* __restrict__ list)
{
    extern __shared__ char lds[];   // 4 waves x 8192 B
    const int tid  = threadIdx.x;
    const int lane = tid & 63;
    const int wid  = tid >> 6;

    const int dd = blockIdx.x;                  // XCD-aware swizzle (4096 % 8 == 0)
    const int w  = (dd & 7) * 512 + (dd >> 3);
    const int colblk = w & 3, rowblk = w >> 2;
    const int c0 = colblk * 128;

    // ---- BN constants for this wave's 128 cols ----
    float invE[4], addE[4], invO[4], addO[4];
    #pragma unroll
    for (int cf = 0; cf < 4; ++cf) {
        const int cE = c0 + cf * 32 + 2 * (lane & 15);
        const int cO = cE + 1;
        const float ivE = gamma[cE] / sqrtf(rvar[cE] + 1e-5f);
        const float ivO = gamma[cO] / sqrtf(rvar[cO] + 1e-5f);
        invE[cf] = ivE; addE[cf] = beta[cE] - rmean[cE] * ivE;
        invO[cf] = ivO; addO[cf] = beta[cO] - rmean[cO] * ivO;
    }
    asm volatile("s_waitcnt vmcnt(0)" ::: "memory");
    __builtin_amdgcn_sched_barrier(0);

    // ---- A staging map: lane -> (row r_l = lane>>1 of wave's 32, half h_l) ----
    const int r_l = lane >> 1, h_l = lane & 1;
    const int rowg = wid * 32 + r_l;                    // row in 128-panel (= sl*4 + t)
    const int t_a = rowg & 3, sl_a = rowg >> 2;
    const unsigned vA = (unsigned)(t_a * 32768 + rowblk * 32 + sl_a) * 2048u
                      + (unsigned)h_l * 64u;

    // LDS write offsets (within wave slab + buf*4096): term stride 2048
    const int swzW = ((r_l >> 1) & 3) << 4;
    const int wb0 = r_l * 64 + ((h_l * 32 + 0)  ^ swzW);
    const int wb1 = r_l * 64 + ((h_l * 32 + 16) ^ swzW);

    // LDS read offsets for A-operand fragments (rf 0,1)
    const int cbA = (lane >> 4) << 4;
    const int rr0 = (lane & 15), rr1 = 16 + (lane & 15);
    const int ra0 = rr0 * 64 + (cbA ^ (((rr0 >> 1) & 3) << 4));
    const int ra1 = rr1 * 64 + (cbA ^ (((rr1 >> 1) & 3) << 4));
    char* ldsw = lds + wid * 8192;

    // ---- B voffsets: [h][term] ----
    unsigned vB[2][2];
    #pragma unroll
    for (int h = 0; h < 2; ++h)
        #pragma unroll
        for (int tm = 0; tm < 2; ++tm)
            vB[h][tm] = ((unsigned)(colblk * 2 + h) << 17) + (unsigned)tm * 4096u
                      + (unsigned)lane * 16u;

    f4 accE[2][4], accO[2][4];
    #pragma unroll
    for (int i = 0; i < 2; ++i)
        #pragma unroll
        for (int j = 0; j < 4; ++j) { accE[i][j] = (f4)0.0f; accO[i][j] = (f4)0.0f; }

    float4 Aa[4], Ab[4];
    bf8 Bf[16];
    bf8 ah0, ah1, am0, am1;

#define SCHED __builtin_amdgcn_sched_barrier(0)

#define ALOAD(AI, K)                                                              \
    do {                                                                          \
        asm volatile("global_load_dwordx4 %0, %1, %2 offset:%3"                   \
                     : "=v"(AI[0]) : "v"(vA), "s"(x), "n"((K)*128 + 0) : "memory");  \
        asm volatile("global_load_dwordx4 %0, %1, %2 offset:%3"                   \
                     : "=v"(AI[1]) : "v"(vA), "s"(x), "n"((K)*128 + 16) : "memory"); \
        asm volatile("global_load_dwordx4 %0, %1, %2 offset:%3"                   \
                     : "=v"(AI[2]) : "v"(vA), "s"(x), "n"((K)*128 + 32) : "memory"); \
        asm volatile("global_load_dwordx4 %0, %1, %2 offset:%3"                   \
                     : "=v"(AI[3]) : "v"(vA), "s"(x), "n"((K)*128 + 48) : "memory"); \
    } while (0)

#define BGRP(G, K)                                                                \
    do {                                                                          \
        asm volatile("global_load_dwordx4 %0, %1, %2 offset:%3"                   \
                     : "=v"(Bf[(G)*4 + 0])                                        \
                     : "v"(vB[(G) >> 1][0] + (unsigned)(K)*8192u), "s"(wp),       \
                       "n"(((G)&1)*2048 + 0) : "memory");                         \
        asm volatile("global_load_dwordx4 %0, %1, %2 offset:%3"                   \
                     : "=v"(Bf[(G)*4 + 1])                                        \
                     : "v"(vB[(G) >> 1][0] + (unsigned)(K)*8192u), "s"(wp),       \
                       "n"(((G)&1)*2048 + 1024) : "memory");                      \
        asm volatile("global_load_dwordx4 %0, %1, %2 offset:%3"                   \
                     : "=v"(Bf[(G)*4 + 2])                                        \
                     : "v"(vB[(G) >> 1][1] + (unsigned)(K)*8192u), "s"(wp),       \
                       "n"(((G)&1)*2048 + 0) : "memory");                         \
        asm volatile("global_load_dwordx4 %0, %1, %2 offset:%3"                   \
                     : "=v"(Bf[(G)*4 + 3])                                        \
                     : "v"(vB[(G) >> 1][1] + (unsigned)(K)*8192u), "s"(wp),       \
                       "n"(((G)&1)*2048 + 1024) : "memory");                      \
    } while (0)

#define CONVWRITE(AC, BUF)                                                        \
    do {                                                                          \
        char* pw = ldsw + (BUF) * 4096;                                           \
        unsigned q0 = cvtpk(AC[0].x, AC[0].y), q1 = cvtpk(AC[0].z, AC[0].w);      \
        unsigned q2 = cvtpk(AC[1].x, AC[1].y), q3 = cvtpk(AC[1].z, AC[1].w);      \
        unsigned r0 = cvtpk(AC[0].x - hi_lo_f(q0), AC[0].y - hi_hi_f(q0));        \
        unsigned r1 = cvtpk(AC[0].z - hi_lo_f(q1), AC[0].w - hi_hi_f(q1));        \
        unsigned r2 = cvtpk(AC[1].x - hi_lo_f(q2), AC[1].y - hi_hi_f(q2));        \
        unsigned r3 = cvtpk(AC[1].z - hi_lo_f(q3), AC[1].w - hi_hi_f(q3));        \
        *(uint4*)(pw + wb0) = make_uint4(q0, q1, q2, q3);                         \
        *(uint4*)(pw + 2048 + wb0) = make_uint4(r0, r1, r2, r3);                  \
        q0 = cvtpk(AC[2].x, AC[2].y); q1 = cvtpk(AC[2].z, AC[2].w);               \
        q2 = cvtpk(AC[3].x, AC[3].y); q3 = cvtpk(AC[3].z, AC[3].w);               \
        r0 = cvtpk(AC[2].x - hi_lo_f(q0), AC[2].y - hi_hi_f(q0));                 \
        r1 = cvtpk(AC[2].z - hi_lo_f(q1), AC[2].w - hi_hi_f(q1));                 \
        r2 = cvtpk(AC[3].x - hi_lo_f(q2), AC[3].y - hi_hi_f(q2));                 \
        r3 = cvtpk(AC[3].z - hi_lo_f(q3), AC[3].w - hi_hi_f(q3));                 \
        *(uint4*)(pw + wb1) = make_uint4(q0, q1, q2, q3);                         \
        *(uint4*)(pw + 2048 + wb1) = make_uint4(r0, r1, r2, r3);                  \
    } while (0)

#define DSREADA(J)                                                                \
    do {                                                                          \
        const char* ldsR = ldsw + ((J) & 1) * 4096;                               \
        ah0 = *(const bf8*)(ldsR + ra0);                                          \
        am0 = *(const bf8*)(ldsR + 2048 + ra0);                                   \
        ah1 = *(const bf8*)(ldsR + ra1);                                          \
        am1 = *(const bf8*)(ldsR + 2048 + ra1);                                   \
    } while (0)

#define MGRP(G)                                                                   \
    do {                                                                          \
        accE[0][G] = __builtin_amdgcn_mfma_f32_16x16x32_bf16(ah0, Bf[(G)*4+0], accE[0][G], 0, 0, 0); \
        accE[1][G] = __builtin_amdgcn_mfma_f32_16x16x32_bf16(ah1, Bf[(G)*4+0], accE[1][G], 0, 0, 0); \
        accO[0][G] = __builtin_amdgcn_mfma_f32_16x16x32_bf16(ah0, Bf[(G)*4+1], accO[0][G], 0, 0, 0); \
        accO[1][G] = __builtin_amdgcn_mfma_f32_16x16x32_bf16(ah1, Bf[(G)*4+1], accO[1][G], 0, 0, 0); \
        accE[0][G] = __builtin_amdgcn_mfma_f32_16x16x32_bf16(ah0, Bf[(G)*4+2], accE[0][G], 0, 0, 0); \
        accE[1][G] = __builtin_amdgcn_mfma_f32_16x16x32_bf16(ah1, Bf[(G)*4+2], accE[1][G], 0, 0, 0); \
        accO[0][G] = __builtin_amdgcn_mfma_f32_16x16x32_bf16(ah0, Bf[(G)*4+3], accO[0][G], 0, 0, 0); \
        accO[1][G] = __builtin_amdgcn_mfma_f32_16x16x32_bf16(ah1, Bf[(G)*4+3], accO[1][G], 0, 0, 0); \
        accE[0][G] = __builtin_amdgcn_mfma_f32_16x16x32_bf16(am0, Bf[(G)*4+0], accE[0][G], 0, 0, 0); \
        accE[1][G] = __builtin_amdgcn_mfma_f32_16x16x32_bf16(am1, Bf[(G)*4+0], accE[1][G], 0, 0, 0); \
        accO[0][G] = __builtin_amdgcn_mfma_f32_16x16x32_bf16(am0, Bf[(G)*4+1], accO[0][G], 0, 0, 0); \
        accO[1][G] = __builtin_amdgcn_mfma_f32_16x16x32_bf16(am1, Bf[(G)*4+1], accO[1][G], 0, 0, 0); \
    } while (0)

#define MBG(G, J)                                                                 \
    do {                                                                          \
        __builtin_amdgcn_s_setprio(1);                                            \
        MGRP(G);                                                                  \
        __builtin_amdgcn_s_setprio(0);                                            \
        SCHED;                                                                    \
        if ((J) + 1 <= 15) { BGRP(G, (J) + 1); }                                  \
        SCHED;                                                                    \
    } while (0)

// Ledger at ITER(J) top: outstanding (oldest first) = {A(J+1):4, B(J):16}.
#define ITER(J, AI, AC, NA, NB)                                                   \
    do {                                                                          \
        SCHED;                                                                    \
        if ((J) + 2 <= 15) { ALOAD(AI, (J) + 2); }                                \
        SCHED;                                                                    \
        if ((J) + 1 <= 15) {                                                      \
            asm volatile("s_waitcnt vmcnt(" NA ")" ::: "memory");                 \
            SCHED;                                                                \
            CONVWRITE(AC, ((J) + 1) & 1);                                         \
            SCHED;                                                                \
        }                                                                         \
        DSREADA(J);                                                               \
        SCHED;                                                                    \
        asm volatile("s_waitcnt vmcnt(" NB ")" ::: "memory");                     \
        SCHED;                                                                    \
        MBG(0, J); MBG(1, J); MBG(2, J); MBG(3, J);                               \
        asm volatile("s_waitcnt lgkmcnt(0)" ::: "memory");                        \
        SCHED;                                                                    \
    } while (0)

    // ---- prologue: A(0)->Aa, A(1)->Ab, B(0); retire A(0); write buf0 ----
    SCHED;
    ALOAD(Aa, 0);
    SCHED;
    ALOAD(Ab, 1);
    SCHED;
    BGRP(0, 0); BGRP(1, 0); BGRP(2, 0); BGRP(3, 0);
    SCHED;
    asm volatile("s_waitcnt vmcnt(20)" ::: "memory");
    SCHED;
    CONVWRITE(Aa, 0);
    SCHED;
    asm volatile("s_waitcnt lgkmcnt(0)" ::: "memory");
    SCHED;

    ITER(0,  Aa, Ab, "20", "4");
    ITER(1,  Ab, Aa, "20", "4");
    ITER(2,  Aa, Ab, "20", "4");
    ITER(3,  Ab, Aa, "20", "4");
    ITER(4,  Aa, Ab, "20", "4");
    ITER(5,  Ab, Aa, "20", "4");
    ITER(6,  Aa, Ab, "20", "4");
    ITER(7,  Ab, Aa, "20", "4");
    ITER(8,  Aa, Ab, "20", "4");
    ITER(9,  Ab, Aa, "20", "4");
    ITER(10, Aa, Ab, "20", "4");
    ITER(11, Ab, Aa, "20", "4");
    ITER(12, Aa, Ab, "20", "4");
    ITER(13, Ab, Aa, "20", "4");
    ITER(14, Aa, Ab, "16", "0");
    ITER(15, Ab, Aa, "0",  "0");

#undef ITER
#undef MBG
#undef MGRP
#undef DSREADA
#undef CONVWRITE
#undef BGRP
#undef ALOAD
#undef SCHED

    // ---- epilogue: BN -> pool -> LIF, flag near-threshold pipelines ----
    #pragma unroll
    for (int rf = 0; rf < 2; ++rf) {
        const int site = rowblk * 32 + wid * 8 + rf * 4 + (lane >> 4);
        const int bI = site >> 10, nI = site & 1023;
        #pragma unroll
        for (int cf = 0; cf < 4; ++cf) {
            const int op = ((c0 + cf * 32) >> 1) + (lane & 15);
            float v = 0.0f;
            bool flg = false;
            #pragma unroll
            for (int t = 0; t < 4; ++t) {
                float hE = accE[rf][cf][t] * invE[cf] + addE[cf];
                float hO = accO[rf][cf][t] * invO[cf] + addO[cf];
                float m = fmaxf(hE, hO);
                v = (v + m) * 0.5f;
                float dv = v - 1.0f;
                bool sp = dv >= 0.0f;
                out[(((size_t)t * 32 + bI) * 1024 + nI) * 256 + op] = sp ? 1.0f : 0.0f;
                flg |= (fabsf(dv) < 2e-4f);
                if (sp) v = 0.0f;
            }
            if (flg) {
                unsigned idx = atomicAdd(cnt, 1u);
                if (idx < CAP) list[idx] = ((unsigned)site << 8) | (unsigned)op;
            }
        }
    }
}

// ---------------- exact f64 repair of flagged pipelines ----------------
__global__ __launch_bounds__(256) void k_repair(
    const float* __restrict__ x, const float* __restrict__ W,
    const float* __restrict__ gamma, const float* __restrict__ beta,
    const float* __restrict__ rmean, const float* __restrict__ rvar,
    float* __restrict__ out, const unsigned* __restrict__ cnt,
    const unsigned* __restrict__ list)
{
    unsigned count = *cnt;
    if (count > CAP) count = CAP;
    for (unsigned j = blockIdx.x * 256 + threadIdx.x; j < count; j += 256u * 256u) {
        const unsigned e = list[j];
        const int op = e & 255;
        const int site = e >> 8;
        const int bI = site >> 10, nI = site & 1023;

        double h[4][2];
        #pragma unroll
        for (int p = 0; p < 2; ++p) {
            const int c = 2 * op + p;
            const float* Wr = W + (size_t)c * D_;
            #pragma unroll
            for (int t = 0; t < 4; ++t) {
                const float* xr = x + (((size_t)t * 32 + bI) * 1024 + nI) * D_;
                double s0 = 0, s1 = 0, s2 = 0, s3 = 0;
                for (int d = 0; d < D_; d += 4) {
                    float4 xv = *(const float4*)(xr + d);
                    float4 wv = *(const float4*)(Wr + d);
                    s0 = fma((double)xv.x, (double)wv.x, s0);
                    s1 = fma((double)xv.y, (double)wv.y, s1);
                    s2 = fma((double)xv.z, (double)wv.z, s2);
                    s3 = fma((double)xv.w, (double)wv.w, s3);
                }
                h[t][p] = (s0 + s1) + (s2 + s3);
            }
        }
        double iv[2], ad[2];
        #pragma unroll
        for (int p = 0; p < 2; ++p) {
            const int c = 2 * op + p;
            iv[p] = (double)gamma[c] / sqrt((double)rvar[c] + 1e-5);
            ad[p] = (double)beta[c] - (double)rmean[c] * iv[p];
        }
        double v = 0.0;
        #pragma unroll
        for (int t = 0; t < 4; ++t) {
            double h0 = h[t][0] * iv[0] + ad[0];
            double h1 = h[t][1] * iv[1] + ad[1];
            double m = fmax(h0, h1);
            v = (v + m) * 0.5;
            const bool sp = (v >= 1.0);
            out[(((size_t)t * 32 + bI) * 1024 + nI) * 256 + op] = sp ? 1.0f : 0.0f;
            if (sp) v = 0.0;
        }
    }
}

// ---------------- fallback (round-1 exact f64 kernel) ----------------
constexpr int FB_SITES = 32, FB_ROWS = 128, FB_BN = 64, FB_BK = 16;

__global__ __launch_bounds__(256)
void snn_fused_f64(const float* __restrict__ x, const float* __restrict__ W,
                   const float* __restrict__ gamma, const float* __restrict__ beta,
                   const float* __restrict__ rmean, const float* __restrict__ rvar,
                   float* __restrict__ out)
{
    __shared__ float As[FB_BK][FB_ROWS];
    __shared__ float Bs[FB_BK][FB_BN];
    const int tid = threadIdx.x;
    const int tx = tid & 15, ty = tid >> 4;
    const int c0 = blockIdx.x * FB_BN;
    const int site_base = blockIdx.y * FB_SITES;
    const int b = site_base / N_, n0 = site_base % N_;
    const int lrow = tid >> 1, lk = (tid & 1) * 8;
    const int s_l = lrow >> 2, t_l = lrow & 3;
    const float* xrow = x + (size_t)((t_l * B_ + b) * N_ + (n0 + s_l)) * D_ + lk;
    const int wc = tid & 63, wk = (tid >> 6) * 4;
    const float* wrow = W + (size_t)(c0 + wc) * D_ + wk;
    double acc[8][4];
    #pragma unroll
    for (int i = 0; i < 8; ++i)
        #pragma unroll
        for (int j = 0; j < 4; ++j) acc[i][j] = 0.0;
    for (int k0 = 0; k0 < D_; k0 += FB_BK) {
        const float4 a0 = *(const float4*)(xrow + k0);
        const float4 a1 = *(const float4*)(xrow + k0 + 4);
        const float4 w4 = *(const float4*)(wrow + k0);
        As[lk + 0][lrow] = a0.x; As[lk + 1][lrow] = a0.y; As[lk + 2][lrow] = a0.z; As[lk + 3][lrow] = a0.w;
        As[lk + 4][lrow] = a1.x; As[lk + 5][lrow] = a1.y; As[lk + 6][lrow] = a1.z; As[lk + 7][lrow] = a1.w;
        Bs[wk + 0][wc] = w4.x; Bs[wk + 1][wc] = w4.y; Bs[wk + 2][wc] = w4.z; Bs[wk + 3][wc] = w4.w;
        __syncthreads();
        #pragma unroll
        for (int k = 0; k < FB_BK; ++k) {
            const float4 af0 = *(const float4*)&As[k][ty * 8];
            const float4 af1 = *(const float4*)&As[k][ty * 8 + 4];
            const float4 bf = *(const float4*)&Bs[k][tx * 4];
            const double ad[8] = {(double)af0.x, (double)af0.y, (double)af0.z, (double)af0.w,
                                  (double)af1.x, (double)af1.y, (double)af1.z, (double)af1.w};
            const double bd[4] = {(double)bf.x, (double)bf.y, (double)bf.z, (double)bf.w};
            #pragma unroll
            for (int i = 0; i < 8; ++i)
                #pragma unroll
                for (int j = 0; j < 4; ++j) acc[i][j] = fma(ad[i], bd[j], acc[i][j]);
        }
        __syncthreads();
    }
    double invd[4], addd[4];
    #pragma unroll
    for (int j = 0; j < 4; ++j) {
        const int c = c0 + tx * 4 + j;
        const double ivv = (double)gamma[c] / sqrt((double)rvar[c] + 1e-5);
        invd[j] = ivv; addd[j] = (double)beta[c] - (double)rmean[c] * ivv;
    }
    #pragma unroll
    for (int si = 0; si < 2; ++si) {
        const int n = n0 + ty * 2 + si;
        #pragma unroll
        for (int p = 0; p < 2; ++p) {
            const int op = (c0 >> 1) + tx * 2 + p;
            double v = 0.0;
            #pragma unroll
            for (int t = 0; t < 4; ++t) {
                const int i = si * 4 + t;
                const double h0 = acc[i][2 * p] * invd[2 * p] + addd[2 * p];
                const double h1 = acc[i][2 * p + 1] * invd[2 * p + 1] + addd[2 * p + 1];
                const double m = fmax(h0, h1);
                v = v + (m - v) * 0.5;
                const bool sp = (v >= 1.0);
                out[((size_t)(t * B_ + b) * N_ + n) * OP_ + op] = sp ? 1.0f : 0.0f;
                if (sp) v = 0.0;
            }
        }
    }
}

extern "C" void kernel_launch(void* const* d_in, const int* in_sizes, int n_in,
                              void* d_out, int out_size, void* d_ws, size_t ws_size,
                              hipStream_t stream)
{
    const float* x     = (const float*)d_in[0];
    const float* W     = (const float*)d_in[1];
    const float* gamma = (const float*)d_in[2];
    const float* beta  = (const float*)d_in[3];
    const float* rmean = (const float*)d_in[4];
    const float* rvar  = (const float*)d_in[5];
    float* out = (float*)d_out;

    if (ws_size < WS_NEED) {
        dim3 grid(O_ / FB_BN, (B_ * N_) / FB_SITES);
        snn_fused_f64<<<grid, dim3(256), 0, stream>>>(x, W, gamma, beta, rmean, rvar, out);
        return;
    }

    char* ws = (char*)d_ws;
    unsigned* cnt = (unsigned*)(ws + WS_CNT);
    unsigned short* wp = (unsigned short*)(ws + WS_WP);
    unsigned* list = (unsigned*)(ws + WS_LIST);

    k_wprep<<<256, 256, 0, stream>>>(W, wp, cnt);
    k_gemm<<<4096, 256, 32768, stream>>>(x, wp, gamma, beta, rmean, rvar, out, cnt, list);
    k_repair<<<256, 256, 0, stream>>>(x, W, gamma, beta, rmean, rvar, out, cnt, list);
}

// Round 9
// 310.428 us; speedup vs baseline: 1.4498x; 1.2484x over previous
//
#include <hip/hip_runtime.h>

constexpr int T_ = 4, B_ = 32, N_ = 1024, D_ = 512, O_ = 512, OP_ = 256;
constexpr int M_ = T_ * B_ * N_;
constexpr unsigned CAP = 1u * 1024 * 1024;

// ---- ws layout (bytes) ----
constexpr size_t WS_CNT  = 0;
constexpr size_t WS_WP   = 1u << 20;                  // 1 MiB fragment-ordered W (hi+lo)
constexpr size_t WS_LIST = WS_WP + (1u << 20);
constexpr size_t WS_NEED = WS_LIST + (size_t)CAP * 4;

typedef __attribute__((ext_vector_type(8))) short bf8;
typedef __attribute__((ext_vector_type(4))) float f4;

__device__ __forceinline__ unsigned cvtpk(float x0, float x1) {
    unsigned r;
    asm("v_cvt_pk_bf16_f32 %0, %1, %2" : "=v"(r) : "v"(x0), "v"(x1));
    return r;
}
__device__ __forceinline__ float hi_lo_f(unsigned u) { return __uint_as_float(u << 16); }
__device__ __forceinline__ float hi_hi_f(unsigned u) { return __uint_as_float(u & 0xffff0000u); }

// ---------------- W prep: fragment-ordered hi/lo split + cnt reset ----------------
// wp chunk id c = [panel:8][j:16][q:8][lane:64], 16B each; q = term*4 + cf*2 + eo.
__global__ __launch_bounds__(256) void k_wprep(const float* __restrict__ W,
                                               unsigned short* __restrict__ wp,
                                               unsigned* __restrict__ cnt)
{
    if (blockIdx.x == 0 && threadIdx.x == 0) *cnt = 0u;
    const int c = blockIdx.x * 256 + threadIdx.x;      // 0..65535
    const int lane = c & 63, q = (c >> 6) & 7, j = (c >> 9) & 15, panel = c >> 13;
    const int colblk = panel >> 1, half = panel & 1;
    const int term = q >> 2, cf = (q >> 1) & 1, eo = q & 1;
    const int col = colblk * 128 + half * 64 + cf * 32 + 2 * (lane & 15) + eo;
    const int k0 = j * 32 + (lane >> 4) * 8;
    const float* src = W + (size_t)col * 512 + k0;
    const float4 v0 = *(const float4*)(src);
    const float4 v1 = *(const float4*)(src + 4);
    const float xs[8] = {v0.x, v0.y, v0.z, v0.w, v1.x, v1.y, v1.z, v1.w};
    unsigned o[4];
    #pragma unroll
    for (int p = 0; p < 4; ++p) {
        const unsigned hi = cvtpk(xs[2 * p], xs[2 * p + 1]);
        if (term == 0) {
            o[p] = hi;
        } else {
            const float l0 = xs[2 * p] - hi_lo_f(hi);
            const float l1 = xs[2 * p + 1] - hi_hi_f(hi);
            o[p] = cvtpk(l0, l1);
        }
    }
    *(uint4*)(wp + (size_t)c * 8) = make_uint4(o[0], o[1], o[2], o[3]);
}

// -------- phase-split (T3+T4+T5) fused GEMM + BN/pool/LIF + flag --------
// 4 waves, 128x128 tile, K-step 32, LDS 32KB: [buf:2][term:2][row:128][64B].
// Per step: 1 barrier, counted per-phase vmcnt (never 0 until tail).
__global__ __launch_bounds__(256, 2) void k_gemm(
    const float* __restrict__ x, const unsigned short* __restrict__ wp,
    const float* __restrict__ gamma, const float* __restrict__ beta,
    const float* __restrict__ rmean, const float* __restrict__ rvar,
    float* __restrict__ out, unsigned* __restrict__ cnt, unsigned* __restrict__ list)
{
    extern __shared__ char lds[];
    const int tid  = threadIdx.x;
    const int lane = tid & 63;
    const int wid  = tid >> 6;

    const int dd = blockIdx.x;                  // XCD-aware swizzle
    const int w  = (dd & 7) * 512 + (dd >> 3);
    const int colblk = w & 3, rowblk = w >> 2;
    const int c0  = colblk * 128;
    const int wr0 = (wid >> 1) * 64, wc0 = (wid & 1) * 64;
    const int cbA = (lane >> 4) << 4;

    // ---- BN constants ----
    float invE[2], addE[2], invO[2], addO[2];
    #pragma unroll
    for (int cf = 0; cf < 2; ++cf) {
        int cE = c0 + wc0 + cf * 32 + 2 * (lane & 15);
        int cO = cE + 1;
        float ivE = gamma[cE] / sqrtf(rvar[cE] + 1e-5f);
        float ivO = gamma[cO] / sqrtf(rvar[cO] + 1e-5f);
        invE[cf] = ivE; addE[cf] = beta[cE] - rmean[cE] * ivE;
        invO[cf] = ivO; addO[cf] = beta[cO] - rmean[cO] * ivO;
    }
    asm volatile("s_waitcnt vmcnt(0)" ::: "memory");
    __builtin_amdgcn_sched_barrier(0);

    // ---- A staging map (2 threads/row): arow 0..127, kh = 16-float half ----
    const int arow = tid >> 1;
    const int kh   = tid & 1;
    const int t_a  = arow & 3;
    const int sl_a = arow >> 2;
    const unsigned vA = (unsigned)(t_a * 32768 + rowblk * 32 + sl_a) * 2048u
                      + (unsigned)kh * 64u;
    const int swzA = ((arow >> 1) & 3) << 4;
    const int wb0 = arow * 64 + ((kh * 32 + 0)  ^ swzA);
    const int wb1 = arow * 64 + ((kh * 32 + 16) ^ swzA);

    // ---- A-fragment LDS read offsets per rf ----
    int raO[4];
    #pragma unroll
    for (int rf = 0; rf < 4; ++rf) {
        const int row = wr0 + rf * 16 + (lane & 15);
        raO[rf] = row * 64 + (cbA ^ (((row >> 1) & 3) << 4));
    }

    // ---- B voffset base (fragment-ordered, coalesced) ----
    const int panel = colblk * 2 + (wid & 1);
    const unsigned vBb = ((unsigned)panel << 17) + (unsigned)lane * 16u;

    f4 accE[4][2], accO[4][2];
    #pragma unroll
    for (int i = 0; i < 4; ++i)
        #pragma unroll
        for (int j = 0; j < 2; ++j) { accE[i][j] = (f4)0.0f; accO[i][j] = (f4)0.0f; }

    float4 Aa[4], Ab[4];
    bf8 Bf[8];
    bf8 ah[4], am[4];

#define SCHED __builtin_amdgcn_sched_barrier(0)

#define ALOAD(AI, K)                                                              \
    do {                                                                          \
        asm volatile("global_load_dwordx4 %0, %1, %2 offset:%3"                   \
                     : "=v"(AI[0]) : "v"(vA), "s"(x), "n"((K)*128 + 0)  : "memory"); \
        asm volatile("global_load_dwordx4 %0, %1, %2 offset:%3"                   \
                     : "=v"(AI[1]) : "v"(vA), "s"(x), "n"((K)*128 + 16) : "memory"); \
        asm volatile("global_load_dwordx4 %0, %1, %2 offset:%3"                   \
                     : "=v"(AI[2]) : "v"(vA), "s"(x), "n"((K)*128 + 32) : "memory"); \
        asm volatile("global_load_dwordx4 %0, %1, %2 offset:%3"                   \
                     : "=v"(AI[3]) : "v"(vA), "s"(x), "n"((K)*128 + 48) : "memory"); \
    } while (0)

// load the 4 B frags of column-family CF (q = term*4 + CF*2 + eo)
#define BGRPC(CF, K)                                                              \
    do {                                                                          \
        const unsigned vk  = vBb + (unsigned)(K) * 8192u;                         \
        const unsigned vk2 = vk + 4096u;                                          \
        asm volatile("global_load_dwordx4 %0, %1, %2 offset:%3"                   \
                     : "=v"(Bf[(CF)*2 + 0]) : "v"(vk),  "s"(wp),                  \
                       "n"((CF)*2048 + 0)    : "memory");                         \
        asm volatile("global_load_dwordx4 %0, %1, %2 offset:%3"                   \
                     : "=v"(Bf[(CF)*2 + 1]) : "v"(vk),  "s"(wp),                  \
                       "n"((CF)*2048 + 1024) : "memory");                         \
        asm volatile("global_load_dwordx4 %0, %1, %2 offset:%3"                   \
                     : "=v"(Bf[4 + (CF)*2]) : "v"(vk2), "s"(wp),                  \
                       "n"((CF)*2048 + 0)    : "memory");                         \
        asm volatile("global_load_dwordx4 %0, %1, %2 offset:%3"                   \
                     : "=v"(Bf[5 + (CF)*2]) : "v"(vk2), "s"(wp),                  \
                       "n"((CF)*2048 + 1024) : "memory");                         \
    } while (0)

#define CONVW(AC, BUF)                                                            \
    do {                                                                          \
        char* pw = lds + (BUF) * 16384;                                           \
        unsigned q0 = cvtpk(AC[0].x, AC[0].y), q1 = cvtpk(AC[0].z, AC[0].w);      \
        unsigned q2 = cvtpk(AC[1].x, AC[1].y), q3 = cvtpk(AC[1].z, AC[1].w);      \
        unsigned r0 = cvtpk(AC[0].x - hi_lo_f(q0), AC[0].y - hi_hi_f(q0));        \
        unsigned r1 = cvtpk(AC[0].z - hi_lo_f(q1), AC[0].w - hi_hi_f(q1));        \
        unsigned r2 = cvtpk(AC[1].x - hi_lo_f(q2), AC[1].y - hi_hi_f(q2));        \
        unsigned r3 = cvtpk(AC[1].z - hi_lo_f(q3), AC[1].w - hi_hi_f(q3));        \
        *(uint4*)(pw + wb0) = make_uint4(q0, q1, q2, q3);                         \
        *(uint4*)(pw + 8192 + wb0) = make_uint4(r0, r1, r2, r3);                  \
        q0 = cvtpk(AC[2].x, AC[2].y); q1 = cvtpk(AC[2].z, AC[2].w);               \
        q2 = cvtpk(AC[3].x, AC[3].y); q3 = cvtpk(AC[3].z, AC[3].w);               \
        r0 = cvtpk(AC[2].x - hi_lo_f(q0), AC[2].y - hi_hi_f(q0));                 \
        r1 = cvtpk(AC[2].z - hi_lo_f(q1), AC[2].w - hi_hi_f(q1));                 \
        r2 = cvtpk(AC[3].x - hi_lo_f(q2), AC[3].y - hi_hi_f(q2));                 \
        r3 = cvtpk(AC[3].z - hi_lo_f(q3), AC[3].w - hi_hi_f(q3));                 \
        *(uint4*)(pw + wb1) = make_uint4(q0, q1, q2, q3);                         \
        *(uint4*)(pw + 8192 + wb1) = make_uint4(r0, r1, r2, r3);                  \
    } while (0)

#define DSREADM(J)                                                                \
    do {                                                                          \
        const char* bR = lds + ((J) & 1) * 16384;                                 \
        ah[0] = *(const bf8*)(bR + raO[0]);  am[0] = *(const bf8*)(bR + 8192 + raO[0]); \
        ah[1] = *(const bf8*)(bR + raO[1]);  am[1] = *(const bf8*)(bR + 8192 + raO[1]); \
        ah[2] = *(const bf8*)(bR + raO[2]);  am[2] = *(const bf8*)(bR + 8192 + raO[2]); \
        ah[3] = *(const bf8*)(bR + raO[3]);  am[3] = *(const bf8*)(bR + 8192 + raO[3]); \
    } while (0)

// 12 MFMAs: rows RA,RB x col-family CF; 4 independent dep-chains interleaved
#define MGRP12(CF, RA, RB)                                                        \
    do {                                                                          \
        accE[RA][CF] = __builtin_amdgcn_mfma_f32_16x16x32_bf16(ah[RA], Bf[0+(CF)*2], accE[RA][CF], 0, 0, 0); \
        accO[RA][CF] = __builtin_amdgcn_mfma_f32_16x16x32_bf16(ah[RA], Bf[1+(CF)*2], accO[RA][CF], 0, 0, 0); \
        accE[RB][CF] = __builtin_amdgcn_mfma_f32_16x16x32_bf16(ah[RB], Bf[0+(CF)*2], accE[RB][CF], 0, 0, 0); \
        accO[RB][CF] = __builtin_amdgcn_mfma_f32_16x16x32_bf16(ah[RB], Bf[1+(CF)*2], accO[RB][CF], 0, 0, 0); \
        accE[RA][CF] = __builtin_amdgcn_mfma_f32_16x16x32_bf16(ah[RA], Bf[4+(CF)*2], accE[RA][CF], 0, 0, 0); \
        accO[RA][CF] = __builtin_amdgcn_mfma_f32_16x16x32_bf16(ah[RA], Bf[5+(CF)*2], accO[RA][CF], 0, 0, 0); \
        accE[RB][CF] = __builtin_amdgcn_mfma_f32_16x16x32_bf16(ah[RB], Bf[4+(CF)*2], accE[RB][CF], 0, 0, 0); \
        accO[RB][CF] = __builtin_amdgcn_mfma_f32_16x16x32_bf16(ah[RB], Bf[5+(CF)*2], accO[RB][CF], 0, 0, 0); \
        accE[RA][CF] = __builtin_amdgcn_mfma_f32_16x16x32_bf16(am[RA], Bf[0+(CF)*2], accE[RA][CF], 0, 0, 0); \
        accO[RA][CF] = __builtin_amdgcn_mfma_f32_16x16x32_bf16(am[RA], Bf[1+(CF)*2], accO[RA][CF], 0, 0, 0); \
        accE[RB][CF] = __builtin_amdgcn_mfma_f32_16x16x32_bf16(am[RB], Bf[0+(CF)*2], accE[RB][CF], 0, 0, 0); \
        accO[RB][CF] = __builtin_amdgcn_mfma_f32_16x16x32_bf16(am[RB], Bf[1+(CF)*2], accO[RB][CF], 0, 0, 0); \
    } while (0)

#define PRIO1 __builtin_amdgcn_s_setprio(1)
#define PRIO0 __builtin_amdgcn_s_setprio(0)

// Ledger at ITER(J) top (J<=13): outstanding = {A(J+1):4, Bcf0(J):4, Bcf1(J):4} = 12.
#define ITER(J, ATGT, ACV)                                                        \
    do {                                                                          \
        SCHED;                                                                    \
        asm volatile("s_waitcnt vmcnt(8)" ::: "memory");     /* A(J+1) ready */   \
        asm volatile("s_waitcnt lgkmcnt(0)" ::: "memory");   /* drain conv */     \
        __builtin_amdgcn_s_barrier();                                             \
        SCHED;                                                                    \
        DSREADM(J);                                                               \
        CONVW(ACV, ((J) + 1) & 1);                                                \
        SCHED;                                                                    \
        asm volatile("s_waitcnt vmcnt(4)" ::: "memory");     /* Bcf0(J) ready */  \
        SCHED;                                                                    \
        PRIO1; MGRP12(0, 0, 1); PRIO0; SCHED;                                     \
        ALOAD(ATGT, (J) + 2); SCHED;                                              \
        PRIO1; MGRP12(0, 2, 3); PRIO0; SCHED;                                     \
        BGRPC(0, (J) + 1); SCHED;                                                 \
        asm volatile("s_waitcnt vmcnt(8)" ::: "memory");     /* Bcf1(J) ready */  \
        SCHED;                                                                    \
        PRIO1; MGRP12(1, 0, 1); PRIO0; SCHED;                                     \
        PRIO1; MGRP12(1, 2, 3); PRIO0; SCHED;                                     \
        BGRPC(1, (J) + 1); SCHED;                                                 \
    } while (0)

    // ---- prologue: A(0),A(1),B(0); retire A0; conv A0 -> buf0 ----
    SCHED;
    ALOAD(Aa, 0);
    ALOAD(Ab, 1);
    SCHED;
    BGRPC(0, 0);
    BGRPC(1, 0);
    SCHED;
    asm volatile("s_waitcnt vmcnt(12)" ::: "memory");   // retire A(0)
    SCHED;
    CONVW(Aa, 0);
    SCHED;

    ITER(0,  Aa, Ab);
    ITER(1,  Ab, Aa);
    ITER(2,  Aa, Ab);
    ITER(3,  Ab, Aa);
    ITER(4,  Aa, Ab);
    ITER(5,  Ab, Aa);
    ITER(6,  Aa, Ab);
    ITER(7,  Ab, Aa);
    ITER(8,  Aa, Ab);
    ITER(9,  Ab, Aa);
    ITER(10, Aa, Ab);
    ITER(11, Ab, Aa);
    ITER(12, Aa, Ab);
    ITER(13, Ab, Aa);

    // ---- J = 14: no ALOAD; conv A15 (in Ab); outstanding top = {A15:4, B14:8} ----
    SCHED;
    asm volatile("s_waitcnt vmcnt(8)" ::: "memory");    // retire A15
    asm volatile("s_waitcnt lgkmcnt(0)" ::: "memory");
    __builtin_amdgcn_s_barrier();
    SCHED;
    DSREADM(14);
    CONVW(Ab, 1);
    SCHED;
    asm volatile("s_waitcnt vmcnt(4)" ::: "memory");    // Bcf0(14) ready
    SCHED;
    PRIO1; MGRP12(0, 0, 1); PRIO0; SCHED;
    PRIO1; MGRP12(0, 2, 3); PRIO0; SCHED;
    BGRPC(0, 15); SCHED;
    asm volatile("s_waitcnt vmcnt(4)" ::: "memory");    // Bcf1(14) ready
    SCHED;
    PRIO1; MGRP12(1, 0, 1); PRIO0; SCHED;
    PRIO1; MGRP12(1, 2, 3); PRIO0; SCHED;
    BGRPC(1, 15); SCHED;

    // ---- J = 15: tail; outstanding top = {B15:8} ----
    asm volatile("s_waitcnt lgkmcnt(0)" ::: "memory");
    __builtin_amdgcn_s_barrier();
    SCHED;
    DSREADM(15);
    SCHED;
    asm volatile("s_waitcnt vmcnt(4)" ::: "memory");    // Bcf0(15) ready
    SCHED;
    PRIO1; MGRP12(0, 0, 1); PRIO0; SCHED;
    PRIO1; MGRP12(0, 2, 3); PRIO0; SCHED;
    asm volatile("s_waitcnt vmcnt(0)" ::: "memory");    // Bcf1(15) ready
    SCHED;
    PRIO1; MGRP12(1, 0, 1); PRIO0; SCHED;
    PRIO1; MGRP12(1, 2, 3); PRIO0; SCHED;

#undef ITER
#undef PRIO1
#undef PRIO0
#undef MGRP12
#undef DSREADM
#undef CONVW
#undef BGRPC
#undef ALOAD
#undef SCHED

    // ---- epilogue: BN -> pool -> LIF, flag near-threshold pipelines ----
    #pragma unroll
    for (int rf = 0; rf < 4; ++rf) {
        const int site = rowblk * 32 + (wid >> 1) * 16 + rf * 4 + (lane >> 4);
        const int bI = site >> 10, nI = site & 1023;
        #pragma unroll
        for (int cf = 0; cf < 2; ++cf) {
            const int op = ((c0 + wc0 + cf * 32) >> 1) + (lane & 15);
            float v = 0.0f;
            bool flg = false;
            #pragma unroll
            for (int t = 0; t < 4; ++t) {
                float hE = accE[rf][cf][t] * invE[cf] + addE[cf];
                float hO = accO[rf][cf][t] * invO[cf] + addO[cf];
                float m = fmaxf(hE, hO);
                v = (v + m) * 0.5f;
                float dv = v - 1.0f;
                bool sp = dv >= 0.0f;
                out[(((size_t)t * 32 + bI) * 1024 + nI) * 256 + op] = sp ? 1.0f : 0.0f;
                flg |= (fabsf(dv) < 1e-4f);
                if (sp) v = 0.0f;
            }
            if (flg) {
                unsigned idx = atomicAdd(cnt, 1u);
                if (idx < CAP) list[idx] = ((unsigned)site << 8) | (unsigned)op;
            }
        }
    }
}

// ---------------- exact f64 repair of flagged pipelines ----------------
__global__ __launch_bounds__(256) void k_repair(
    const float* __restrict__ x, const float* __restrict__ W,
    const float* __restrict__ gamma, const float* __restrict__ beta,
    const float* __restrict__ rmean, const float* __restrict__ rvar,
    float* __restrict__ out, const unsigned* __restrict__ cnt,
    const unsigned* __restrict__ list)
{
    unsigned count = *cnt;
    if (count > CAP) count = CAP;
    for (unsigned j = blockIdx.x * 256 + threadIdx.x; j < count; j += 256u * 256u) {
        const unsigned e = list[j];
        const int op = e & 255;
        const int site = e >> 8;
        const int bI = site >> 10, nI = site & 1023;

        double h[4][2];
        #pragma unroll
        for (int p = 0; p < 2; ++p) {
            const int c = 2 * op + p;
            const float* Wr = W + (size_t)c * D_;
            #pragma unroll
            for (int t = 0; t < 4; ++t) {
                const float* xr = x + (((size_t)t * 32 + bI) * 1024 + nI) * D_;
                double s0 = 0, s1 = 0, s2 = 0, s3 = 0;
                for (int d = 0; d < D_; d += 4) {
                    float4 xv = *(const float4*)(xr + d);
                    float4 wv = *(const float4*)(Wr + d);
                    s0 = fma((double)xv.x, (double)wv.x, s0);
                    s1 = fma((double)xv.y, (double)wv.y, s1);
                    s2 = fma((double)xv.z, (double)wv.z, s2);
                    s3 = fma((double)xv.w, (double)wv.w, s3);
                }
                h[t][p] = (s0 + s1) + (s2 + s3);
            }
        }
        double iv[2], ad[2];
        #pragma unroll
        for (int p = 0; p < 2; ++p) {
            const int c = 2 * op + p;
            iv[p] = (double)gamma[c] / sqrt((double)rvar[c] + 1e-5);
            ad[p] = (double)beta[c] - (double)rmean[c] * iv[p];
        }
        double v = 0.0;
        #pragma unroll
        for (int t = 0; t < 4; ++t) {
            double h0 = h[t][0] * iv[0] + ad[0];
            double h1 = h[t][1] * iv[1] + ad[1];
            double m = fmax(h0, h1);
            v = (v + m) * 0.5;
            const bool sp = (v >= 1.0);
            out[(((size_t)t * 32 + bI) * 1024 + nI) * 256 + op] = sp ? 1.0f : 0.0f;
            if (sp) v = 0.0;
        }
    }
}

// ---------------- fallback (round-1 exact f64 kernel) ----------------
constexpr int FB_SITES = 32, FB_ROWS = 128, FB_BN = 64, FB_BK = 16;

__global__ __launch_bounds__(256)
void snn_fused_f64(const float* __restrict__ x, const float* __restrict__ W,
                   const float* __restrict__ gamma, const float* __restrict__ beta,
                   const float* __restrict__ rmean, const float* __restrict__ rvar,
                   float* __restrict__ out)
{
    __shared__ float As[FB_BK][FB_ROWS];
    __shared__ float Bs[FB_BK][FB_BN];
    const int tid = threadIdx.x;
    const int tx = tid & 15, ty = tid >> 4;
    const int c0 = blockIdx.x * FB_BN;
    const int site_base = blockIdx.y * FB_SITES;
    const int b = site_base / N_, n0 = site_base % N_;
    const int lrow = tid >> 1, lk = (tid & 1) * 8;
    const int s_l = lrow >> 2, t_l = lrow & 3;
    const float* xrow = x + (size_t)((t_l * B_ + b) * N_ + (n0 + s_l)) * D_ + lk;
    const int wc = tid & 63, wk = (tid >> 6) * 4;
    const float* wrow = W + (size_t)(c0 + wc) * D_ + wk;
    double acc[8][4];
    #pragma unroll
    for (int i = 0; i < 8; ++i)
        #pragma unroll
        for (int j = 0; j < 4; ++j) acc[i][j] = 0.0;
    for (int k0 = 0; k0 < D_; k0 += FB_BK) {
        const float4 a0 = *(const float4*)(xrow + k0);
        const float4 a1 = *(const float4*)(xrow + k0 + 4);
        const float4 w4 = *(const float4*)(wrow + k0);
        As[lk + 0][lrow] = a0.x; As[lk + 1][lrow] = a0.y; As[lk + 2][lrow] = a0.z; As[lk + 3][lrow] = a0.w;
        As[lk + 4][lrow] = a1.x; As[lk + 5][lrow] = a1.y; As[lk + 6][lrow] = a1.z; As[lk + 7][lrow] = a1.w;
        Bs[wk + 0][wc] = w4.x; Bs[wk + 1][wc] = w4.y; Bs[wk + 2][wc] = w4.z; Bs[wk + 3][wc] = w4.w;
        __syncthreads();
        #pragma unroll
        for (int k = 0; k < FB_BK; ++k) {
            const float4 af0 = *(const float4*)&As[k][ty * 8];
            const float4 af1 = *(const float4*)&As[k][ty * 8 + 4];
            const float4 bf = *(const float4*)&Bs[k][tx * 4];
            const double ad[8] = {(double)af0.x, (double)af0.y, (double)af0.z, (double)af0.w,
                                  (double)af1.x, (double)af1.y, (double)af1.z, (double)af1.w};
            const double bd[4] = {(double)bf.x, (double)bf.y, (double)bf.z, (double)bf.w};
            #pragma unroll
            for (int i = 0; i < 8; ++i)
                #pragma unroll
                for (int j = 0; j < 4; ++j) acc[i][j] = fma(ad[i], bd[j], acc[i][j]);
        }
        __syncthreads();
    }
    double invd[4], addd[4];
    #pragma unroll
    for (int j = 0; j < 4; ++j) {
        const int c = c0 + tx * 4 + j;
        const double ivv = (double)gamma[c] / sqrt((double)rvar[c] + 1e-5);
        invd[j] = ivv; addd[j] = (double)beta[c] - (double)rmean[c] * ivv;
    }
    #pragma unroll
    for (int si = 0; si < 2; ++si) {
        const int n = n0 + ty * 2 + si;
        #pragma unroll
        for (int p = 0; p < 2; ++p) {
            const int op = (c0 >> 1) + tx * 2 + p;
            double v = 0.0;
            #pragma unroll
            for (int t = 0; t < 4; ++t) {
                const int i = si * 4 + t;
                const double h0 = acc[i][2 * p] * invd[2 * p] + addd[2 * p];
                const double h1 = acc[i][2 * p + 1] * invd[2 * p + 1] + addd[2 * p + 1];
                const double m = fmax(h0, h1);
                v = v + (m - v) * 0.5;
                const bool sp = (v >= 1.0);
                out[((size_t)(t * B_ + b) * N_ + n) * OP_ + op] = sp ? 1.0f : 0.0f;
                if (sp) v = 0.0;
            }
        }
    }
}

extern "C" void kernel_launch(void* const* d_in, const int* in_sizes, int n_in,
                              void* d_out, int out_size, void* d_ws, size_t ws_size,
                              hipStream_t stream)
{
    const float* x     = (const float*)d_in[0];
    const float* W     = (const float*)d_in[1];
    const float* gamma = (const float*)d_in[2];
    const float* beta  = (const float*)d_in[3];
    const float* rmean = (const float*)d_in[4];
    const float* rvar  = (const float*)d_in[5];
    float* out = (float*)d_out;

    if (ws_size < WS_NEED) {
        dim3 grid(O_ / FB_BN, (B_ * N_) / FB_SITES);
        snn_fused_f64<<<grid, dim3(256), 0, stream>>>(x, W, gamma, beta, rmean, rvar, out);
        return;
    }

    char* ws = (char*)d_ws;
    unsigned* cnt = (unsigned*)(ws + WS_CNT);
    unsigned short* wp = (unsigned short*)(ws + WS_WP);
    unsigned* list = (unsigned*)(ws + WS_LIST);

    k_wprep<<<256, 256, 0, stream>>>(W, wp, cnt);
    k_gemm<<<4096, 256, 32768, stream>>>(x, wp, gamma, beta, rmean, rvar, out, cnt, list);
    k_repair<<<256, 256, 0, stream>>>(x, W, gamma, beta, rmean, rvar, out, cnt, list);
}

// Round 10
// 299.990 us; speedup vs baseline: 1.5002x; 1.0348x over previous
//
#include <hip/hip_runtime.h>

constexpr int T_ = 4, B_ = 32, N_ = 1024, D_ = 512, O_ = 512, OP_ = 256;
constexpr int M_ = T_ * B_ * N_;
constexpr unsigned CAP = 1u * 1024 * 1024;

// ---- ws layout (bytes) ----
constexpr size_t WS_CNT  = 0;
constexpr size_t WS_WP   = 1u << 20;                  // 1 MiB fragment-ordered W (hi+lo)
constexpr size_t WS_LIST = WS_WP + (1u << 20);
constexpr size_t WS_NEED = WS_LIST + (size_t)CAP * 4;

typedef __attribute__((ext_vector_type(8))) short bf8;
typedef __attribute__((ext_vector_type(4))) float f4;

__device__ __forceinline__ unsigned cvtpk(float x0, float x1) {
    unsigned r;
    asm("v_cvt_pk_bf16_f32 %0, %1, %2" : "=v"(r) : "v"(x0), "v"(x1));
    return r;
}
__device__ __forceinline__ float hi_lo_f(unsigned u) { return __uint_as_float(u << 16); }
__device__ __forceinline__ float hi_hi_f(unsigned u) { return __uint_as_float(u & 0xffff0000u); }

// ---------------- W prep: fragment-ordered hi/lo split + cnt reset ----------------
// wp chunk id c = [panel:8][j:16][q:8][lane:64], 16B each; q = term*4 + cf*2 + eo.
__global__ __launch_bounds__(256) void k_wprep(const float* __restrict__ W,
                                               unsigned short* __restrict__ wp,
                                               unsigned* __restrict__ cnt)
{
    if (blockIdx.x == 0 && threadIdx.x == 0) *cnt = 0u;
    const int c = blockIdx.x * 256 + threadIdx.x;      // 0..65535
    const int lane = c & 63, q = (c >> 6) & 7, j = (c >> 9) & 15, panel = c >> 13;
    const int colblk = panel >> 1, half = panel & 1;
    const int term = q >> 2, cf = (q >> 1) & 1, eo = q & 1;
    const int col = colblk * 128 + half * 64 + cf * 32 + 2 * (lane & 15) + eo;
    const int k0 = j * 32 + (lane >> 4) * 8;
    const float* src = W + (size_t)col * 512 + k0;
    const float4 v0 = *(const float4*)(src);
    const float4 v1 = *(const float4*)(src + 4);
    const float xs[8] = {v0.x, v0.y, v0.z, v0.w, v1.x, v1.y, v1.z, v1.w};
    unsigned o[4];
    #pragma unroll
    for (int p = 0; p < 4; ++p) {
        const unsigned hi = cvtpk(xs[2 * p], xs[2 * p + 1]);
        if (term == 0) {
            o[p] = hi;
        } else {
            const float l0 = xs[2 * p] - hi_lo_f(hi);
            const float l1 = xs[2 * p + 1] - hi_hi_f(hi);
            o[p] = cvtpk(l0, l1);
        }
    }
    *(uint4*)(wp + (size_t)c * 8) = make_uint4(o[0], o[1], o[2], o[3]);
}

// -------- phase-split (T3+T4+T5) fused GEMM + BN/pool/LIF + flag --------
// 4 waves, 128x128 tile, K-step 32, LDS 32KB: [buf:2][term:2][row:128][64B].
// Per step: 1 barrier, counted per-phase vmcnt (never 0 until tail).
// launch_bounds(256,3): force 3 waves/EU residency (152 regs/wave fits <=170).
__global__ __launch_bounds__(256, 3) void k_gemm(
    const float* __restrict__ x, const unsigned short* __restrict__ wp,
    const float* __restrict__ gamma, const float* __restrict__ beta,
    const float* __restrict__ rmean, const float* __restrict__ rvar,
    float* __restrict__ out, unsigned* __restrict__ cnt, unsigned* __restrict__ list)
{
    extern __shared__ char lds[];
    const int tid  = threadIdx.x;
    const int lane = tid & 63;
    const int wid  = tid >> 6;

    const int dd = blockIdx.x;                  // XCD-aware swizzle
    const int w  = (dd & 7) * 512 + (dd >> 3);
    const int colblk = w & 3, rowblk = w >> 2;
    const int c0  = colblk * 128;
    const int wr0 = (wid >> 1) * 64, wc0 = (wid & 1) * 64;
    const int cbA = (lane >> 4) << 4;

    // ---- BN constants ----
    float invE[2], addE[2], invO[2], addO[2];
    #pragma unroll
    for (int cf = 0; cf < 2; ++cf) {
        int cE = c0 + wc0 + cf * 32 + 2 * (lane & 15);
        int cO = cE + 1;
        float ivE = gamma[cE] / sqrtf(rvar[cE] + 1e-5f);
        float ivO = gamma[cO] / sqrtf(rvar[cO] + 1e-5f);
        invE[cf] = ivE; addE[cf] = beta[cE] - rmean[cE] * ivE;
        invO[cf] = ivO; addO[cf] = beta[cO] - rmean[cO] * ivO;
    }
    asm volatile("s_waitcnt vmcnt(0)" ::: "memory");
    __builtin_amdgcn_sched_barrier(0);

    // ---- A staging map (2 threads/row): arow 0..127, kh = 16-float half ----
    const int arow = tid >> 1;
    const int kh   = tid & 1;
    const int t_a  = arow & 3;
    const int sl_a = arow >> 2;
    const unsigned vA = (unsigned)(t_a * 32768 + rowblk * 32 + sl_a) * 2048u
                      + (unsigned)kh * 64u;
    const int swzA = ((arow >> 1) & 3) << 4;
    const int wb0 = arow * 64 + ((kh * 32 + 0)  ^ swzA);
    const int wb1 = arow * 64 + ((kh * 32 + 16) ^ swzA);

    // ---- A-fragment LDS read offsets per rf ----
    int raO[4];
    #pragma unroll
    for (int rf = 0; rf < 4; ++rf) {
        const int row = wr0 + rf * 16 + (lane & 15);
        raO[rf] = row * 64 + (cbA ^ (((row >> 1) & 3) << 4));
    }

    // ---- B voffset base (fragment-ordered, coalesced) ----
    const int panel = colblk * 2 + (wid & 1);
    const unsigned vBb = ((unsigned)panel << 17) + (unsigned)lane * 16u;

    f4 accE[4][2], accO[4][2];
    #pragma unroll
    for (int i = 0; i < 4; ++i)
        #pragma unroll
        for (int j = 0; j < 2; ++j) { accE[i][j] = (f4)0.0f; accO[i][j] = (f4)0.0f; }

    float4 Aa[4], Ab[4];
    bf8 Bf[8];
    bf8 ah[4], am[4];

#define SCHED __builtin_amdgcn_sched_barrier(0)

#define ALOAD(AI, K)                                                              \
    do {                                                                          \
        asm volatile("global_load_dwordx4 %0, %1, %2 offset:%3"                   \
                     : "=v"(AI[0]) : "v"(vA), "s"(x), "n"((K)*128 + 0)  : "memory"); \
        asm volatile("global_load_dwordx4 %0, %1, %2 offset:%3"                   \
                     : "=v"(AI[1]) : "v"(vA), "s"(x), "n"((K)*128 + 16) : "memory"); \
        asm volatile("global_load_dwordx4 %0, %1, %2 offset:%3"                   \
                     : "=v"(AI[2]) : "v"(vA), "s"(x), "n"((K)*128 + 32) : "memory"); \
        asm volatile("global_load_dwordx4 %0, %1, %2 offset:%3"                   \
                     : "=v"(AI[3]) : "v"(vA), "s"(x), "n"((K)*128 + 48) : "memory"); \
    } while (0)

// load the 4 B frags of column-family CF (q = term*4 + CF*2 + eo)
#define BGRPC(CF, K)                                                              \
    do {                                                                          \
        const unsigned vk  = vBb + (unsigned)(K) * 8192u;                         \
        const unsigned vk2 = vk + 4096u;                                          \
        asm volatile("global_load_dwordx4 %0, %1, %2 offset:%3"                   \
                     : "=v"(Bf[(CF)*2 + 0]) : "v"(vk),  "s"(wp),                  \
                       "n"((CF)*2048 + 0)    : "memory");                         \
        asm volatile("global_load_dwordx4 %0, %1, %2 offset:%3"                   \
                     : "=v"(Bf[(CF)*2 + 1]) : "v"(vk),  "s"(wp),                  \
                       "n"((CF)*2048 + 1024) : "memory");                         \
        asm volatile("global_load_dwordx4 %0, %1, %2 offset:%3"                   \
                     : "=v"(Bf[4 + (CF)*2]) : "v"(vk2), "s"(wp),                  \
                       "n"((CF)*2048 + 0)    : "memory");                         \
        asm volatile("global_load_dwordx4 %0, %1, %2 offset:%3"                   \
                     : "=v"(Bf[5 + (CF)*2]) : "v"(vk2), "s"(wp),                  \
                       "n"((CF)*2048 + 1024) : "memory");                         \
    } while (0)

#define CONVW(AC, BUF)                                                            \
    do {                                                                          \
        char* pw = lds + (BUF) * 16384;                                           \
        unsigned q0 = cvtpk(AC[0].x, AC[0].y), q1 = cvtpk(AC[0].z, AC[0].w);      \
        unsigned q2 = cvtpk(AC[1].x, AC[1].y), q3 = cvtpk(AC[1].z, AC[1].w);      \
        unsigned r0 = cvtpk(AC[0].x - hi_lo_f(q0), AC[0].y - hi_hi_f(q0));        \
        unsigned r1 = cvtpk(AC[0].z - hi_lo_f(q1), AC[0].w - hi_hi_f(q1));        \
        unsigned r2 = cvtpk(AC[1].x - hi_lo_f(q2), AC[1].y - hi_hi_f(q2));        \
        unsigned r3 = cvtpk(AC[1].z - hi_lo_f(q3), AC[1].w - hi_hi_f(q3));        \
        *(uint4*)(pw + wb0) = make_uint4(q0, q1, q2, q3);                         \
        *(uint4*)(pw + 8192 + wb0) = make_uint4(r0, r1, r2, r3);                  \
        q0 = cvtpk(AC[2].x, AC[2].y); q1 = cvtpk(AC[2].z, AC[2].w);               \
        q2 = cvtpk(AC[3].x, AC[3].y); q3 = cvtpk(AC[3].z, AC[3].w);               \
        r0 = cvtpk(AC[2].x - hi_lo_f(q0), AC[2].y - hi_hi_f(q0));                 \
        r1 = cvtpk(AC[2].z - hi_lo_f(q1), AC[2].w - hi_hi_f(q1));                 \
        r2 = cvtpk(AC[3].x - hi_lo_f(q2), AC[3].y - hi_hi_f(q2));                 \
        r3 = cvtpk(AC[3].z - hi_lo_f(q3), AC[3].w - hi_hi_f(q3));                 \
        *(uint4*)(pw + wb1) = make_uint4(q0, q1, q2, q3);                         \
        *(uint4*)(pw + 8192 + wb1) = make_uint4(r0, r1, r2, r3);                  \
    } while (0)

#define DSREADM(J)                                                                \
    do {                                                                          \
        const char* bR = lds + ((J) & 1) * 16384;                                 \
        ah[0] = *(const bf8*)(bR + raO[0]);  am[0] = *(const bf8*)(bR + 8192 + raO[0]); \
        ah[1] = *(const bf8*)(bR + raO[1]);  am[1] = *(const bf8*)(bR + 8192 + raO[1]); \
        ah[2] = *(const bf8*)(bR + raO[2]);  am[2] = *(const bf8*)(bR + 8192 + raO[2]); \
        ah[3] = *(const bf8*)(bR + raO[3]);  am[3] = *(const bf8*)(bR + 8192 + raO[3]); \
    } while (0)

// 12 MFMAs: rows RA,RB x col-family CF; 4 independent dep-chains interleaved
#define MGRP12(CF, RA, RB)                                                        \
    do {                                                                          \
        accE[RA][CF] = __builtin_amdgcn_mfma_f32_16x16x32_bf16(ah[RA], Bf[0+(CF)*2], accE[RA][CF], 0, 0, 0); \
        accO[RA][CF] = __builtin_amdgcn_mfma_f32_16x16x32_bf16(ah[RA], Bf[1+(CF)*2], accO[RA][CF], 0, 0, 0); \
        accE[RB][CF] = __builtin_amdgcn_mfma_f32_16x16x32_bf16(ah[RB], Bf[0+(CF)*2], accE[RB][CF], 0, 0, 0); \
        accO[RB][CF] = __builtin_amdgcn_mfma_f32_16x16x32_bf16(ah[RB], Bf[1+(CF)*2], accO[RB][CF], 0, 0, 0); \
        accE[RA][CF] = __builtin_amdgcn_mfma_f32_16x16x32_bf16(ah[RA], Bf[4+(CF)*2], accE[RA][CF], 0, 0, 0); \
        accO[RA][CF] = __builtin_amdgcn_mfma_f32_16x16x32_bf16(ah[RA], Bf[5+(CF)*2], accO[RA][CF], 0, 0, 0); \
        accE[RB][CF] = __builtin_amdgcn_mfma_f32_16x16x32_bf16(ah[RB], Bf[4+(CF)*2], accE[RB][CF], 0, 0, 0); \
        accO[RB][CF] = __builtin_amdgcn_mfma_f32_16x16x32_bf16(ah[RB], Bf[5+(CF)*2], accO[RB][CF], 0, 0, 0); \
        accE[RA][CF] = __builtin_amdgcn_mfma_f32_16x16x32_bf16(am[RA], Bf[0+(CF)*2], accE[RA][CF], 0, 0, 0); \
        accO[RA][CF] = __builtin_amdgcn_mfma_f32_16x16x32_bf16(am[RA], Bf[1+(CF)*2], accO[RA][CF], 0, 0, 0); \
        accE[RB][CF] = __builtin_amdgcn_mfma_f32_16x16x32_bf16(am[RB], Bf[0+(CF)*2], accE[RB][CF], 0, 0, 0); \
        accO[RB][CF] = __builtin_amdgcn_mfma_f32_16x16x32_bf16(am[RB], Bf[1+(CF)*2], accO[RB][CF], 0, 0, 0); \
    } while (0)

#define PRIO1 __builtin_amdgcn_s_setprio(1)
#define PRIO0 __builtin_amdgcn_s_setprio(0)

// Ledger at ITER(J) top (J<=13): outstanding = {A(J+1):4, Bcf0(J):4, Bcf1(J):4} = 12.
#define ITER(J, ATGT, ACV)                                                        \
    do {                                                                          \
        SCHED;                                                                    \
        asm volatile("s_waitcnt vmcnt(8)" ::: "memory");     /* A(J+1) ready */   \
        asm volatile("s_waitcnt lgkmcnt(0)" ::: "memory");   /* drain conv */     \
        __builtin_amdgcn_s_barrier();                                             \
        SCHED;                                                                    \
        DSREADM(J);                                                               \
        CONVW(ACV, ((J) + 1) & 1);                                                \
        SCHED;                                                                    \
        asm volatile("s_waitcnt vmcnt(4)" ::: "memory");     /* Bcf0(J) ready */  \
        SCHED;                                                                    \
        PRIO1; MGRP12(0, 0, 1); PRIO0; SCHED;                                     \
        ALOAD(ATGT, (J) + 2); SCHED;                                              \
        PRIO1; MGRP12(0, 2, 3); PRIO0; SCHED;                                     \
        BGRPC(0, (J) + 1); SCHED;                                                 \
        asm volatile("s_waitcnt vmcnt(8)" ::: "memory");     /* Bcf1(J) ready */  \
        SCHED;                                                                    \
        PRIO1; MGRP12(1, 0, 1); PRIO0; SCHED;                                     \
        PRIO1; MGRP12(1, 2, 3); PRIO0; SCHED;                                     \
        BGRPC(1, (J) + 1); SCHED;                                                 \
    } while (0)

    // ---- prologue: A(0),A(1),B(0); retire A0; conv A0 -> buf0 ----
    SCHED;
    ALOAD(Aa, 0);
    ALOAD(Ab, 1);
    SCHED;
    BGRPC(0, 0);
    BGRPC(1, 0);
    SCHED;
    asm volatile("s_waitcnt vmcnt(12)" ::: "memory");   // retire A(0)
    SCHED;
    CONVW(Aa, 0);
    SCHED;

    ITER(0,  Aa, Ab);
    ITER(1,  Ab, Aa);
    ITER(2,  Aa, Ab);
    ITER(3,  Ab, Aa);
    ITER(4,  Aa, Ab);
    ITER(5,  Ab, Aa);
    ITER(6,  Aa, Ab);
    ITER(7,  Ab, Aa);
    ITER(8,  Aa, Ab);
    ITER(9,  Ab, Aa);
    ITER(10, Aa, Ab);
    ITER(11, Ab, Aa);
    ITER(12, Aa, Ab);
    ITER(13, Ab, Aa);

    // ---- J = 14: no ALOAD; conv A15 (in Ab); outstanding top = {A15:4, B14:8} ----
    SCHED;
    asm volatile("s_waitcnt vmcnt(8)" ::: "memory");    // retire A15
    asm volatile("s_waitcnt lgkmcnt(0)" ::: "memory");
    __builtin_amdgcn_s_barrier();
    SCHED;
    DSREADM(14);
    CONVW(Ab, 1);
    SCHED;
    asm volatile("s_waitcnt vmcnt(4)" ::: "memory");    // Bcf0(14) ready
    SCHED;
    PRIO1; MGRP12(0, 0, 1); PRIO0; SCHED;
    PRIO1; MGRP12(0, 2, 3); PRIO0; SCHED;
    BGRPC(0, 15); SCHED;
    asm volatile("s_waitcnt vmcnt(4)" ::: "memory");    // Bcf1(14) ready
    SCHED;
    PRIO1; MGRP12(1, 0, 1); PRIO0; SCHED;
    PRIO1; MGRP12(1, 2, 3); PRIO0; SCHED;
    BGRPC(1, 15); SCHED;

    // ---- J = 15: tail; outstanding top = {B15:8} ----
    asm volatile("s_waitcnt lgkmcnt(0)" ::: "memory");
    __builtin_amdgcn_s_barrier();
    SCHED;
    DSREADM(15);
    SCHED;
    asm volatile("s_waitcnt vmcnt(4)" ::: "memory");    // Bcf0(15) ready
    SCHED;
    PRIO1; MGRP12(0, 0, 1); PRIO0; SCHED;
    PRIO1; MGRP12(0, 2, 3); PRIO0; SCHED;
    asm volatile("s_waitcnt vmcnt(0)" ::: "memory");    // Bcf1(15) ready
    SCHED;
    PRIO1; MGRP12(1, 0, 1); PRIO0; SCHED;
    PRIO1; MGRP12(1, 2, 3); PRIO0; SCHED;

#undef ITER
#undef PRIO1
#undef PRIO0
#undef MGRP12
#undef DSREADM
#undef CONVW
#undef BGRPC
#undef ALOAD
#undef SCHED

    // ---- epilogue: BN -> pool -> LIF, flag near-threshold pipelines ----
    #pragma unroll
    for (int rf = 0; rf < 4; ++rf) {
        const int site = rowblk * 32 + (wid >> 1) * 16 + rf * 4 + (lane >> 4);
        const int bI = site >> 10, nI = site & 1023;
        #pragma unroll
        for (int cf = 0; cf < 2; ++cf) {
            const int op = ((c0 + wc0 + cf * 32) >> 1) + (lane & 15);
            float v = 0.0f;
            bool flg = false;
            #pragma unroll
            for (int t = 0; t < 4; ++t) {
                float hE = accE[rf][cf][t] * invE[cf] + addE[cf];
                float hO = accO[rf][cf][t] * invO[cf] + addO[cf];
                float m = fmaxf(hE, hO);
                v = (v + m) * 0.5f;
                float dv = v - 1.0f;
                bool sp = dv >= 0.0f;
                out[(((size_t)t * 32 + bI) * 1024 + nI) * 256 + op] = sp ? 1.0f : 0.0f;
                flg |= (fabsf(dv) < 1e-4f);
                if (sp) v = 0.0f;
            }
            if (flg) {
                unsigned idx = atomicAdd(cnt, 1u);
                if (idx < CAP) list[idx] = ((unsigned)site << 8) | (unsigned)op;
            }
        }
    }
}

// ---------------- exact f64 repair of flagged pipelines ----------------
__global__ __launch_bounds__(256) void k_repair(
    const float* __restrict__ x, const float* __restrict__ W,
    const float* __restrict__ gamma, const float* __restrict__ beta,
    const float* __restrict__ rmean, const float* __restrict__ rvar,
    float* __restrict__ out, const unsigned* __restrict__ cnt,
    const unsigned* __restrict__ list)
{
    unsigned count = *cnt;
    if (count > CAP) count = CAP;
    for (unsigned j = blockIdx.x * 256 + threadIdx.x; j < count; j += 256u * 256u) {
        const unsigned e = list[j];
        const int op = e & 255;
        const int site = e >> 8;
        const int bI = site >> 10, nI = site & 1023;

        double h[4][2];
        #pragma unroll
        for (int p = 0; p < 2; ++p) {
            const int c = 2 * op + p;
            const float* Wr = W + (size_t)c * D_;
            #pragma unroll
            for (int t = 0; t < 4; ++t) {
                const float* xr = x + (((size_t)t * 32 + bI) * 1024 + nI) * D_;
                double s0 = 0, s1 = 0, s2 = 0, s3 = 0;
                for (int d = 0; d < D_; d += 4) {
                    float4 xv = *(const float4*)(xr + d);
                    float4 wv = *(const float4*)(Wr + d);
                    s0 = fma((double)xv.x, (double)wv.x, s0);
                    s1 = fma((double)xv.y, (double)wv.y, s1);
                    s2 = fma((double)xv.z, (double)wv.z, s2);
                    s3 = fma((double)xv.w, (double)wv.w, s3);
                }
                h[t][p] = (s0 + s1) + (s2 + s3);
            }
        }
        double iv[2], ad[2];
        #pragma unroll
        for (int p = 0; p < 2; ++p) {
            const int c = 2 * op + p;
            iv[p] = (double)gamma[c] / sqrt((double)rvar[c] + 1e-5);
            ad[p] = (double)beta[c] - (double)rmean[c] * iv[p];
        }
        double v = 0.0;
        #pragma unroll
        for (int t = 0; t < 4; ++t) {
            double h0 = h[t][0] * iv[0] + ad[0];
            double h1 = h[t][1] * iv[1] + ad[1];
            double m = fmax(h0, h1);
            v = (v + m) * 0.5;
            const bool sp = (v >= 1.0);
            out[(((size_t)t * 32 + bI) * 1024 + nI) * 256 + op] = sp ? 1.0f : 0.0f;
            if (sp) v = 0.0;
        }
    }
}

// ---------------- fallback (round-1 exact f64 kernel) ----------------
constexpr int FB_SITES = 32, FB_ROWS = 128, FB_BN = 64, FB_BK = 16;

__global__ __launch_bounds__(256)
void snn_fused_f64(const float* __restrict__ x, const float* __restrict__ W,
                   const float* __restrict__ gamma, const float* __restrict__ beta,
                   const float* __restrict__ rmean, const float* __restrict__ rvar,
                   float* __restrict__ out)
{
    __shared__ float As[FB_BK][FB_ROWS];
    __shared__ float Bs[FB_BK][FB_BN];
    const int tid = threadIdx.x;
    const int tx = tid & 15, ty = tid >> 4;
    const int c0 = blockIdx.x * FB_BN;
    const int site_base = blockIdx.y * FB_SITES;
    const int b = site_base / N_, n0 = site_base % N_;
    const int lrow = tid >> 1, lk = (tid & 1) * 8;
    const int s_l = lrow >> 2, t_l = lrow & 3;
    const float* xrow = x + (size_t)((t_l * B_ + b) * N_ + (n0 + s_l)) * D_ + lk;
    const int wc = tid & 63, wk = (tid >> 6) * 4;
    const float* wrow = W + (size_t)(c0 + wc) * D_ + wk;
    double acc[8][4];
    #pragma unroll
    for (int i = 0; i < 8; ++i)
        #pragma unroll
        for (int j = 0; j < 4; ++j) acc[i][j] = 0.0;
    for (int k0 = 0; k0 < D_; k0 += FB_BK) {
        const float4 a0 = *(const float4*)(xrow + k0);
        const float4 a1 = *(const float4*)(xrow + k0 + 4);
        const float4 w4 = *(const float4*)(wrow + k0);
        As[lk + 0][lrow] = a0.x; As[lk + 1][lrow] = a0.y; As[lk + 2][lrow] = a0.z; As[lk + 3][lrow] = a0.w;
        As[lk + 4][lrow] = a1.x; As[lk + 5][lrow] = a1.y; As[lk + 6][lrow] = a1.z; As[lk + 7][lrow] = a1.w;
        Bs[wk + 0][wc] = w4.x; Bs[wk + 1][wc] = w4.y; Bs[wk + 2][wc] = w4.z; Bs[wk + 3][wc] = w4.w;
        __syncthreads();
        #pragma unroll
        for (int k = 0; k < FB_BK; ++k) {
            const float4 af0 = *(const float4*)&As[k][ty * 8];
            const float4 af1 = *(const float4*)&As[k][ty * 8 + 4];
            const float4 bf = *(const float4*)&Bs[k][tx * 4];
            const double ad[8] = {(double)af0.x, (double)af0.y, (double)af0.z, (double)af0.w,
                                  (double)af1.x, (double)af1.y, (double)af1.z, (double)af1.w};
            const double bd[4] = {(double)bf.x, (double)bf.y, (double)bf.z, (double)bf.w};
            #pragma unroll
            for (int i = 0; i < 8; ++i)
                #pragma unroll
                for (int j = 0; j < 4; ++j) acc[i][j] = fma(ad[i], bd[j], acc[i][j]);
        }
        __syncthreads();
    }
    double invd[4], addd[4];
    #pragma unroll
    for (int j = 0; j < 4; ++j) {
        const int c = c0 + tx * 4 + j;
        const double ivv = (double)gamma[c] / sqrt((double)rvar[c] + 1e-5);
        invd[j] = ivv; addd[j] = (double)beta[c] - (double)rmean[c] * ivv;
    }
    #pragma unroll
    for (int si = 0; si < 2; ++si) {
        const int n = n0 + ty * 2 + si;
        #pragma unroll
        for (int p = 0; p < 2; ++p) {
            const int op = (c0 >> 1) + tx * 2 + p;
            double v = 0.0;
            #pragma unroll
            for (int t = 0; t < 4; ++t) {
                const int i = si * 4 + t;
                const double h0 = acc[i][2 * p] * invd[2 * p] + addd[2 * p];
                const double h1 = acc[i][2 * p + 1] * invd[2 * p + 1] + addd[2 * p + 1];
                const double m = fmax(h0, h1);
                v = v + (m - v) * 0.5;
                const bool sp = (v >= 1.0);
                out[((size_t)(t * B_ + b) * N_ + n) * OP_ + op] = sp ? 1.0f : 0.0f;
                if (sp) v = 0.0;
            }
        }
    }
}

extern "C" void kernel_launch(void* const* d_in, const int* in_sizes, int n_in,
                              void* d_out, int out_size, void* d_ws, size_t ws_size,
                              hipStream_t stream)
{
    const float* x     = (const float*)d_in[0];
    const float* W     = (const float*)d_in[1];
    const float* gamma = (const float*)d_in[2];
    const float* beta  = (const float*)d_in[3];
    const float* rmean = (const float*)d_in[4];
    const float* rvar  = (const float*)d_in[5];
    float* out = (float*)d_out;

    if (ws_size < WS_NEED) {
        dim3 grid(O_ / FB_BN, (B_ * N_) / FB_SITES);
        snn_fused_f64<<<grid, dim3(256), 0, stream>>>(x, W, gamma, beta, rmean, rvar, out);
        return;
    }

    char* ws = (char*)d_ws;
    unsigned* cnt = (unsigned*)(ws + WS_CNT);
    unsigned short* wp = (unsigned short*)(ws + WS_WP);
    unsigned* list = (unsigned*)(ws + WS_LIST);

    k_wprep<<<256, 256, 0, stream>>>(W, wp, cnt);
    k_gemm<<<4096, 256, 32768, stream>>>(x, wp, gamma, beta, rmean, rvar, out, cnt, list);
    k_repair<<<256, 256, 0, stream>>>(x, W, gamma, beta, rmean, rvar, out, cnt, list);
}